// Round 5
// baseline (869.361 us; speedup 1.0000x reference)
//
#include <hip/hip_runtime.h>
#include <math.h>

#define PP 3
#define HH 4
#define DD 32
#define FF 128   // H*D
#define INF_ 128 // input feature dim
#define NEG_SLOPE 0.2f
#define NPART 8      // dst partitions ~ XCDs
#define K4CHUNK 8192 // edges per scatter block
#define NB 16        // nodes per wave in k1/k6

__device__ __forceinline__ unsigned int bf16pair(float x, float y) {
    unsigned int a = __float_as_uint(x);
    unsigned int b = __float_as_uint(y);
    a = (a + 0x7FFFu + ((a >> 16) & 1u)) >> 16;   // RNE round to bf16
    b = (b + 0x7FFFu + ((b >> 16) & 1u)) >> 16;
    return a | (b << 16);
}

// K1: feat[p] = h @ W[p] (stored bf16-packed); el/er reductions fp32.
// 4 waves/block, NB=16 nodes/wave, lane l owns cols 2l,2l+1. acc[] kept in
// VGPRs (all indices compile-time constant; tail rows clamped, stores predicated).
__global__ __launch_bounds__(256) void k1_gemm(const float* __restrict__ h, const float* __restrict__ W,
                        const float* __restrict__ al, const float* __restrict__ ar,
                        unsigned int* __restrict__ featb, float* __restrict__ el,
                        float* __restrict__ er, int N) {
    int l = threadIdx.x & 63;
    int wu = __builtin_amdgcn_readfirstlane(threadIdx.x >> 6);
    int p = blockIdx.y;
    int nbase = blockIdx.x * (4 * NB) + wu * NB;
    if (nbase >= N) return;
    const float* Wp = W + (size_t)p * INF_ * FF;
    int c0 = 2 * l;
    int maxoff = N - 1 - nbase;
    size_t roff[NB];
#pragma unroll
    for (int nn = 0; nn < NB; ++nn)
        roff[nn] = (size_t)(nn < maxoff ? nn : maxoff) * INF_;
    const float* hb = h + (size_t)nbase * INF_;

    float2 acc[NB];
#pragma unroll
    for (int i = 0; i < NB; ++i) acc[i] = make_float2(0.f, 0.f);

    for (int k = 0; k < INF_; k += 4) {
        float2 wv0 = *(const float2*)&Wp[(k + 0) * FF + c0];
        float2 wv1 = *(const float2*)&Wp[(k + 1) * FF + c0];
        float2 wv2 = *(const float2*)&Wp[(k + 2) * FF + c0];
        float2 wv3 = *(const float2*)&Wp[(k + 3) * FF + c0];
#pragma unroll
        for (int nn = 0; nn < NB; ++nn) {
            float4 hv = *(const float4*)&hb[roff[nn] + k];   // wave-uniform -> s_load
            acc[nn].x = fmaf(hv.x, wv0.x, acc[nn].x);
            acc[nn].y = fmaf(hv.x, wv0.y, acc[nn].y);
            acc[nn].x = fmaf(hv.y, wv1.x, acc[nn].x);
            acc[nn].y = fmaf(hv.y, wv1.y, acc[nn].y);
            acc[nn].x = fmaf(hv.z, wv2.x, acc[nn].x);
            acc[nn].y = fmaf(hv.z, wv2.y, acc[nn].y);
            acc[nn].x = fmaf(hv.w, wv3.x, acc[nn].x);
            acc[nn].y = fmaf(hv.w, wv3.y, acc[nn].y);
        }
    }

    int hd = l >> 4;
    int d0 = (2 * l) & 31;
    float2 alv = *(const float2*)&al[(p * HH + hd) * DD + d0];
    float2 arv = *(const float2*)&ar[(p * HH + hd) * DD + d0];
#pragma unroll
    for (int nn = 0; nn < NB; ++nn) {
        bool valid = nn <= maxoff;
        int n = nbase + nn;
        float pl = acc[nn].x * alv.x + acc[nn].y * alv.y;
        float pr = acc[nn].x * arv.x + acc[nn].y * arv.y;
        for (int off = 8; off >= 1; off >>= 1) {
            pl += __shfl_xor(pl, off);
            pr += __shfl_xor(pr, off);
        }
        if (valid) {
            featb[((size_t)p * N + n) * 64 + l] = bf16pair(acc[nn].x, acc[nn].y);
            if ((l & 15) == 0) {
                size_t eb = ((size_t)p * N + n) * HH + hd;
                el[eb] = pl;
                er[eb] = pr;
            }
        }
    }
}

// K2: histogram of dst degrees
__global__ void k2_hist(const int* __restrict__ dst, int* __restrict__ counts,
                        int E, int N) {
    int p = blockIdx.y;
    int i = blockIdx.x * 256 + threadIdx.x;
    if (i < E) atomicAdd(&counts[(size_t)p * N + dst[(size_t)p * E + i]], 1);
}

// K3: exclusive prefix sum over counts -> offs (N+1), cursor copy. one block per path.
__global__ __launch_bounds__(1024) void k3_scan(const int* __restrict__ counts,
                                                int* __restrict__ offs,
                                                int* __restrict__ cursor, int N) {
    __shared__ int lds[1024];
    int p = blockIdx.x;
    int t = threadIdx.x;
    int chunk = (N + 1023) / 1024;
    int base = t * chunk;
    int end = base + chunk; if (end > N) end = N; if (base > N) base = N;
    int s = 0;
    for (int i = base; i < end; ++i) s += counts[(size_t)p * N + i];
    lds[t] = s;
    __syncthreads();
    for (int off = 1; off < 1024; off <<= 1) {
        int v = (t >= off) ? lds[t - off] : 0;
        __syncthreads();
        lds[t] += v;
        __syncthreads();
    }
    int run = lds[t] - s;  // exclusive prefix for this thread
    for (int i = base; i < end; ++i) {
        offs[(size_t)p * (N + 1) + i] = run;
        cursor[(size_t)p * N + i] = run;
        run += counts[(size_t)p * N + i];
    }
    if (t == 0) offs[(size_t)p * (N + 1) + N] = lds[1023];
}

// K4: scatter src ids into CSR slots AND compute per-(edge,head) softmax
// weights w = exp(leaky(el[src]+er[dst])) once, stored fp32 in CSR order.
// dst-partitioned (stride-8 block families -> per-XCD L2 write combining).
__global__ __launch_bounds__(256) void k4_scatter(const int* __restrict__ src, const int* __restrict__ dst,
                           int* __restrict__ cursor, int* __restrict__ csr,
                           const float* __restrict__ el, const float* __restrict__ er,
                           float* __restrict__ wtab, int E, int N) {
    int p = blockIdx.y;
    int part = blockIdx.x & (NPART - 1);
    int chunk = blockIdx.x >> 3;
    int pw = (N + NPART - 1) / NPART;
    int lo = part * pw;
    int hi = lo + pw; if (hi > N) hi = N;
    int base = chunk * K4CHUNK;
    int end = base + K4CHUNK; if (end > E) end = E;
    const int* sp = src + (size_t)p * E;
    const int* dp = dst + (size_t)p * E;
    int* cur = cursor + (size_t)p * N;
    int* cp = csr + (size_t)p * E;
    const float* elp = el + (size_t)p * N * HH;
    const float* erp = er + (size_t)p * N * HH;
    float* wp = wtab + (size_t)p * E * HH;

    auto emit = [&](int d, int s) {
        int pos = atomicAdd(&cur[d], 1);
        cp[pos] = s;
        float4 ev = *(const float4*)&elp[(size_t)s * HH];
        float4 rv = *(const float4*)&erp[(size_t)d * HH];
        float4 w4;
        float e;
        e = ev.x + rv.x; e = fmaxf(e, NEG_SLOPE * e); w4.x = __expf(e);
        e = ev.y + rv.y; e = fmaxf(e, NEG_SLOPE * e); w4.y = __expf(e);
        e = ev.z + rv.z; e = fmaxf(e, NEG_SLOPE * e); w4.z = __expf(e);
        e = ev.w + rv.w; e = fmaxf(e, NEG_SLOPE * e); w4.w = __expf(e);
        *(float4*)&wp[(size_t)pos * HH] = w4;
    };

    if ((E & 3) == 0) {
        for (int i = base + 4 * (int)threadIdx.x; i < end; i += 1024) {
            int4 d4 = *(const int4*)&dp[i];
            int4 s4 = *(const int4*)&sp[i];
            if (d4.x >= lo && d4.x < hi) emit(d4.x, s4.x);
            if (d4.y >= lo && d4.y < hi) emit(d4.y, s4.y);
            if (d4.z >= lo && d4.z < hi) emit(d4.z, s4.z);
            if (d4.w >= lo && d4.w < hi) emit(d4.w, s4.w);
        }
    } else {
        for (int i = base + (int)threadIdx.x; i < end; i += 256) {
            int d = dp[i];
            if (d >= lo && d < hi) emit(d, sp[i]);
        }
    }
}

// K5: per-(node,path) weighted aggregation with precomputed CSR-ordered
// weights (sequential wtab stream, L1-line reuse). Lane l owns cols 2l,2l+1.
__global__ __launch_bounds__(256) void k5_aggregate(const unsigned int* __restrict__ featb,
                             const float* __restrict__ wtab, const float* __restrict__ bias,
                             const int* __restrict__ offs, const int* __restrict__ csr,
                             float* __restrict__ z, int N, int E) {
    int w = threadIdx.x >> 6, l = threadIdx.x & 63;
    int n = blockIdx.x * 4 + w;
    int p = blockIdx.y;
    if (n >= N) return;
    int hd = l >> 4;
    int c0 = 2 * l;
    int j0 = offs[(size_t)p * (N + 1) + n];
    int j1 = offs[(size_t)p * (N + 1) + n + 1];
    const int* cs = csr + (size_t)p * E;
    const float* wtp = wtab + (size_t)p * E * HH + hd;
    const unsigned int* fp = featb + (size_t)p * N * 64;
    float acc0 = 0.f, acc1 = 0.f, sumw = 0.f;
    for (int base = j0; base < j1; base += 64) {
        int rem = j1 - base;
        int cnt = rem > 64 ? 64 : rem;
        int mysn = (l < cnt) ? cs[base + l] : 0;   // coalesced batch load of edge srcs
        const float* wt = wtp + (size_t)base * HH;
        int tt = 0;
        for (; tt + 2 <= cnt; tt += 2) {
            int sa = __shfl(mysn, tt);
            int sb = __shfl(mysn, tt + 1);
            float wa = wt[(size_t)tt * HH];
            float wb = wt[(size_t)(tt + 1) * HH];
            unsigned int va = fp[(size_t)sa * 64 + l];
            unsigned int vb = fp[(size_t)sb * 64 + l];
            acc0 = fmaf(wa, __uint_as_float(va << 16), acc0);
            acc1 = fmaf(wa, __uint_as_float(va & 0xFFFF0000u), acc1);
            sumw += wa;
            acc0 = fmaf(wb, __uint_as_float(vb << 16), acc0);
            acc1 = fmaf(wb, __uint_as_float(vb & 0xFFFF0000u), acc1);
            sumw += wb;
        }
        if (tt < cnt) {
            int sa = __shfl(mysn, tt);
            float wa = wt[(size_t)tt * HH];
            unsigned int va = fp[(size_t)sa * 64 + l];
            acc0 = fmaf(wa, __uint_as_float(va << 16), acc0);
            acc1 = fmaf(wa, __uint_as_float(va & 0xFFFF0000u), acc1);
            sumw += wa;
        }
    }
    float inv = 1.f / sumw;   // self-loops guarantee sumw > 0
    float2 bv = *(const float2*)&bias[p * FF + c0];
    float z0 = acc0 * inv + bv.x;
    float z1 = acc1 * inv + bv.y;
    z0 = z0 > 0.f ? z0 : __expf(z0) - 1.f;
    z1 = z1 > 0.f ? z1 : __expf(z1) - 1.f;
    size_t zb = ((size_t)p * N + n) * FF;
    *(float2*)&z[zb + c0] = make_float2(z0, z1);
}

// K6: s[n,p] = tanh(z @ W1 + b1) @ W2; NB nodes/wave register tiling.
__global__ __launch_bounds__(256) void k6_semantic(const float* __restrict__ z, const float* __restrict__ W1,
                            const float* __restrict__ b1, const float* __restrict__ W2,
                            float* __restrict__ partials, int N) {
    __shared__ float wsum[4];
    int t = threadIdx.x;
    int l = t & 63;
    int wu = __builtin_amdgcn_readfirstlane(t >> 6);
    int p = blockIdx.y;
    int nbase = blockIdx.x * (4 * NB) + wu * NB;
    int c0 = 2 * l;
    float ssum = 0.f;
    if (nbase < N) {
        int maxoff = N - 1 - nbase;
        size_t roff[NB];
#pragma unroll
        for (int nn = 0; nn < NB; ++nn)
            roff[nn] = (size_t)(nn < maxoff ? nn : maxoff) * FF;
        const float* zb = z + ((size_t)p * N + nbase) * FF;
        float2 acc[NB];
#pragma unroll
        for (int i = 0; i < NB; ++i) acc[i] = make_float2(0.f, 0.f);
        for (int k = 0; k < FF; k += 4) {
            float2 wv0 = *(const float2*)&W1[(k + 0) * FF + c0];
            float2 wv1 = *(const float2*)&W1[(k + 1) * FF + c0];
            float2 wv2 = *(const float2*)&W1[(k + 2) * FF + c0];
            float2 wv3 = *(const float2*)&W1[(k + 3) * FF + c0];
#pragma unroll
            for (int nn = 0; nn < NB; ++nn) {
                float4 zv = *(const float4*)&zb[roff[nn] + k];   // wave-uniform -> s_load
                acc[nn].x = fmaf(zv.x, wv0.x, acc[nn].x);
                acc[nn].y = fmaf(zv.x, wv0.y, acc[nn].y);
                acc[nn].x = fmaf(zv.y, wv1.x, acc[nn].x);
                acc[nn].y = fmaf(zv.y, wv1.y, acc[nn].y);
                acc[nn].x = fmaf(zv.z, wv2.x, acc[nn].x);
                acc[nn].y = fmaf(zv.z, wv2.y, acc[nn].y);
                acc[nn].x = fmaf(zv.w, wv3.x, acc[nn].x);
                acc[nn].y = fmaf(zv.w, wv3.y, acc[nn].y);
            }
        }
        float2 b1v = *(const float2*)&b1[c0];
        float2 w2v = *(const float2*)&W2[c0];
#pragma unroll
        for (int nn = 0; nn < NB; ++nn) {
            bool valid = nn <= maxoff;
            float a0 = acc[nn].x + b1v.x;
            float a1 = acc[nn].y + b1v.y;
            // tanh(x) = 1 - 2/(exp(2x)+1)  (safe at +/-inf)
            float e0 = __expf(2.f * a0);
            float e1 = __expf(2.f * a1);
            float t0 = 1.f - 2.f * __builtin_amdgcn_rcpf(e0 + 1.f);
            float t1 = 1.f - 2.f * __builtin_amdgcn_rcpf(e1 + 1.f);
            ssum += valid ? (t0 * w2v.x + t1 * w2v.y) : 0.f;
        }
    }
    for (int off = 32; off >= 1; off >>= 1) ssum += __shfl_xor(ssum, off);
    if (l == 0) wsum[wu] = ssum;
    __syncthreads();
    if (t == 0)
        partials[(size_t)p * gridDim.x + blockIdx.x] = wsum[0] + wsum[1] + wsum[2] + wsum[3];
}

// K7: reduce partials -> w[p] mean -> beta softmax. one block, 3 waves.
__global__ void k7_beta(const float* __restrict__ partials, float* __restrict__ beta,
                        int nblk, int N) {
    __shared__ float wl[3];
    int p = threadIdx.x >> 6, l = threadIdx.x & 63;
    float s = 0.f;
    for (int i = l; i < nblk; i += 64) s += partials[(size_t)p * nblk + i];
    for (int off = 32; off >= 1; off >>= 1) s += __shfl_xor(s, off);
    if (l == 0) wl[p] = s / (float)N;
    __syncthreads();
    if (threadIdx.x == 0) {
        float m = fmaxf(wl[0], fmaxf(wl[1], wl[2]));
        float e0 = __expf(wl[0] - m), e1 = __expf(wl[1] - m), e2 = __expf(wl[2] - m);
        float inv = 1.f / (e0 + e1 + e2);
        beta[0] = e0 * inv; beta[1] = e1 * inv; beta[2] = e2 * inv;
    }
}

// K8: out[n,:] = sum_p beta[p] * z[p][n,:]
__global__ void k8_combine(const float* __restrict__ z, const float* __restrict__ beta,
                           float* __restrict__ out, int N) {
    size_t i = (size_t)blockIdx.x * 256 + threadIdx.x;
    size_t tot = (size_t)N * FF;
    if (i < tot) {
        float b0 = beta[0], b1 = beta[1], b2 = beta[2];
        out[i] = b0 * z[i] + b1 * z[tot + i] + b2 * z[2 * tot + i];
    }
}

extern "C" void kernel_launch(void* const* d_in, const int* in_sizes, int n_in,
                              void* d_out, int out_size, void* d_ws, size_t ws_size,
                              hipStream_t stream) {
    const float* h    = (const float*)d_in[0];
    const float* W    = (const float*)d_in[1];
    const float* al   = (const float*)d_in[2];
    const float* ar   = (const float*)d_in[3];
    const float* bias = (const float*)d_in[4];
    const float* W1   = (const float*)d_in[5];
    const float* b1   = (const float*)d_in[6];
    const float* W2   = (const float*)d_in[7];
    const int*   src  = (const int*)d_in[8];
    const int*   dst  = (const int*)d_in[9];
    float* out = (float*)d_out;

    int N = in_sizes[0] / INF_;
    int E = in_sizes[8] / PP;

    char* ws = (char*)d_ws;
    size_t off = 0;
    auto take = [&](size_t bytes) -> void* {
        off = (off + 255) & ~(size_t)255;
        void* ptr = ws + off;
        off += bytes;
        return ptr;
    };
    unsigned int* featb = (unsigned int*)take((size_t)PP * N * 64 * sizeof(unsigned int));
    float* z        = (float*)take((size_t)PP * N * FF * sizeof(float));
    float* el       = (float*)take((size_t)PP * N * HH * sizeof(float));
    float* er       = (float*)take((size_t)PP * N * HH * sizeof(float));
    int*   counts   = (int*)take((size_t)PP * N * sizeof(int));
    int*   offs     = (int*)take((size_t)PP * (N + 1) * sizeof(int));
    int*   cursor   = (int*)take((size_t)PP * N * sizeof(int));
    int*   csr      = (int*)take((size_t)PP * E * sizeof(int));
    float* wtab     = (float*)take((size_t)PP * E * HH * sizeof(float));
    int    nblk64   = (N + 4 * NB - 1) / (4 * NB);
    int    nblk4    = (N + 3) / 4;
    float* partials = (float*)take((size_t)PP * nblk64 * sizeof(float));
    float* betap    = (float*)take(16);
    (void)ws_size; (void)n_in; (void)out_size;

    hipMemsetAsync(counts, 0, (size_t)PP * N * sizeof(int), stream);

    dim3 gTile(nblk64, PP);
    dim3 gNode(nblk4, PP);
    dim3 gEdge((E + 255) / 256, PP);
    dim3 gScat(((E + K4CHUNK - 1) / K4CHUNK) * NPART, PP);

    k1_gemm<<<gTile, 256, 0, stream>>>(h, W, al, ar, featb, el, er, N);
    k2_hist<<<gEdge, 256, 0, stream>>>(dst, counts, E, N);
    k3_scan<<<PP, 1024, 0, stream>>>(counts, offs, cursor, N);
    k4_scatter<<<gScat, 256, 0, stream>>>(src, dst, cursor, csr, el, er, wtab, E, N);
    k5_aggregate<<<gNode, 256, 0, stream>>>(featb, wtab, bias, offs, csr, z, N, E);
    k6_semantic<<<gTile, 256, 0, stream>>>(z, W1, b1, W2, partials, N);
    k7_beta<<<1, 192, 0, stream>>>(partials, betap, nblk64, N);
    k8_combine<<<(int)(((size_t)N * FF + 255) / 256), 256, 0, stream>>>(z, betap, out, N);
}

// Round 6
// 800.173 us; speedup vs baseline: 1.0865x; 1.0865x over previous
//
#include <hip/hip_runtime.h>
#include <math.h>

#define PP 3
#define HH 4
#define DD 32
#define FF 128   // H*D
#define INF_ 128 // input feature dim
#define NEG_SLOPE 0.2f
#define NPART 8      // dst partitions ~ XCDs
#define K4CHUNK 8192 // edges per scatter block
#define NB 16        // nodes per wave in k1/k6

__device__ __forceinline__ unsigned int bf16pair(float x, float y) {
    unsigned int a = __float_as_uint(x);
    unsigned int b = __float_as_uint(y);
    a = (a + 0x7FFFu + ((a >> 16) & 1u)) >> 16;   // RNE round to bf16
    b = (b + 0x7FFFu + ((b >> 16) & 1u)) >> 16;
    return a | (b << 16);
}

// K1: feat[p] = h @ W[p] (stored bf16-packed); el/er reductions fp32.
// 4 waves/block, NB=16 nodes/wave, lane l owns cols 2l,2l+1. acc[] kept in
// VGPRs (all indices compile-time constant; tail rows clamped, stores predicated).
__global__ __launch_bounds__(256) void k1_gemm(const float* __restrict__ h, const float* __restrict__ W,
                        const float* __restrict__ al, const float* __restrict__ ar,
                        unsigned int* __restrict__ featb, float* __restrict__ el,
                        float* __restrict__ er, int N) {
    int l = threadIdx.x & 63;
    int wu = __builtin_amdgcn_readfirstlane(threadIdx.x >> 6);
    int p = blockIdx.y;
    int nbase = blockIdx.x * (4 * NB) + wu * NB;
    if (nbase >= N) return;
    const float* Wp = W + (size_t)p * INF_ * FF;
    int c0 = 2 * l;
    int maxoff = N - 1 - nbase;
    size_t roff[NB];
#pragma unroll
    for (int nn = 0; nn < NB; ++nn)
        roff[nn] = (size_t)(nn < maxoff ? nn : maxoff) * INF_;
    const float* hb = h + (size_t)nbase * INF_;

    float2 acc[NB];
#pragma unroll
    for (int i = 0; i < NB; ++i) acc[i] = make_float2(0.f, 0.f);

    for (int k = 0; k < INF_; k += 4) {
        float2 wv0 = *(const float2*)&Wp[(k + 0) * FF + c0];
        float2 wv1 = *(const float2*)&Wp[(k + 1) * FF + c0];
        float2 wv2 = *(const float2*)&Wp[(k + 2) * FF + c0];
        float2 wv3 = *(const float2*)&Wp[(k + 3) * FF + c0];
#pragma unroll
        for (int nn = 0; nn < NB; ++nn) {
            float4 hv = *(const float4*)&hb[roff[nn] + k];   // wave-uniform -> s_load
            acc[nn].x = fmaf(hv.x, wv0.x, acc[nn].x);
            acc[nn].y = fmaf(hv.x, wv0.y, acc[nn].y);
            acc[nn].x = fmaf(hv.y, wv1.x, acc[nn].x);
            acc[nn].y = fmaf(hv.y, wv1.y, acc[nn].y);
            acc[nn].x = fmaf(hv.z, wv2.x, acc[nn].x);
            acc[nn].y = fmaf(hv.z, wv2.y, acc[nn].y);
            acc[nn].x = fmaf(hv.w, wv3.x, acc[nn].x);
            acc[nn].y = fmaf(hv.w, wv3.y, acc[nn].y);
        }
    }

    int hd = l >> 4;
    int d0 = (2 * l) & 31;
    float2 alv = *(const float2*)&al[(p * HH + hd) * DD + d0];
    float2 arv = *(const float2*)&ar[(p * HH + hd) * DD + d0];
#pragma unroll
    for (int nn = 0; nn < NB; ++nn) {
        bool valid = nn <= maxoff;
        int n = nbase + nn;
        float pl = acc[nn].x * alv.x + acc[nn].y * alv.y;
        float pr = acc[nn].x * arv.x + acc[nn].y * arv.y;
        for (int off = 8; off >= 1; off >>= 1) {
            pl += __shfl_xor(pl, off);
            pr += __shfl_xor(pr, off);
        }
        if (valid) {
            featb[((size_t)p * N + n) * 64 + l] = bf16pair(acc[nn].x, acc[nn].y);
            if ((l & 15) == 0) {
                size_t eb = ((size_t)p * N + n) * HH + hd;
                el[eb] = pl;
                er[eb] = pr;
            }
        }
    }
}

// K2: histogram of dst degrees
__global__ void k2_hist(const int* __restrict__ dst, int* __restrict__ counts,
                        int E, int N) {
    int p = blockIdx.y;
    int i = blockIdx.x * 256 + threadIdx.x;
    if (i < E) atomicAdd(&counts[(size_t)p * N + dst[(size_t)p * E + i]], 1);
}

// K3: exclusive prefix sum over counts -> offs (N+1), cursor copy. one block per path.
__global__ __launch_bounds__(1024) void k3_scan(const int* __restrict__ counts,
                                                int* __restrict__ offs,
                                                int* __restrict__ cursor, int N) {
    __shared__ int lds[1024];
    int p = blockIdx.x;
    int t = threadIdx.x;
    int chunk = (N + 1023) / 1024;
    int base = t * chunk;
    int end = base + chunk; if (end > N) end = N; if (base > N) base = N;
    int s = 0;
    for (int i = base; i < end; ++i) s += counts[(size_t)p * N + i];
    lds[t] = s;
    __syncthreads();
    for (int off = 1; off < 1024; off <<= 1) {
        int v = (t >= off) ? lds[t - off] : 0;
        __syncthreads();
        lds[t] += v;
        __syncthreads();
    }
    int run = lds[t] - s;  // exclusive prefix for this thread
    for (int i = base; i < end; ++i) {
        offs[(size_t)p * (N + 1) + i] = run;
        cursor[(size_t)p * N + i] = run;
        run += counts[(size_t)p * N + i];
    }
    if (t == 0) offs[(size_t)p * (N + 1) + N] = lds[1023];
}

// K4: scatter src ids into CSR slots, dst-partitioned (stride-8 block
// families -> per-XCD L2 write combining). NO per-edge payload beyond the
// 4B src id: R4 showed scattered 16B writes cause RFO + 4x amplification.
__global__ __launch_bounds__(256) void k4_scatter(const int* __restrict__ src, const int* __restrict__ dst,
                           int* __restrict__ cursor, int* __restrict__ csr,
                           int E, int N) {
    int p = blockIdx.y;
    int part = blockIdx.x & (NPART - 1);
    int chunk = blockIdx.x >> 3;
    int pw = (N + NPART - 1) / NPART;
    int lo = part * pw;
    int hi = lo + pw; if (hi > N) hi = N;
    int base = chunk * K4CHUNK;
    int end = base + K4CHUNK; if (end > E) end = E;
    const int* sp = src + (size_t)p * E;
    const int* dp = dst + (size_t)p * E;
    int* cur = cursor + (size_t)p * N;
    int* cp = csr + (size_t)p * E;
    if ((E & 3) == 0) {
        for (int i = base + 4 * (int)threadIdx.x; i < end; i += 1024) {
            int4 d4 = *(const int4*)&dp[i];
            int4 s4 = *(const int4*)&sp[i];
            if (d4.x >= lo && d4.x < hi) cp[atomicAdd(&cur[d4.x], 1)] = s4.x;
            if (d4.y >= lo && d4.y < hi) cp[atomicAdd(&cur[d4.y], 1)] = s4.y;
            if (d4.z >= lo && d4.z < hi) cp[atomicAdd(&cur[d4.z], 1)] = s4.z;
            if (d4.w >= lo && d4.w < hi) cp[atomicAdd(&cur[d4.w], 1)] = s4.w;
        }
    } else {
        for (int i = base + (int)threadIdx.x; i < end; i += 256) {
            int d = dp[i];
            if (d >= lo && d < hi) cp[atomicAdd(&cur[d], 1)] = sp[i];
        }
    }
}

// K5: per-(node,path) single-pass softmax aggregation. Weight computation is
// batch-parallel: each lane computes all 4 head-exps for ITS one loaded edge
// (4 exps/edge total instead of 64), stashes to LDS; inner loop does a
// broadcast ds_read per edge. Same-wave LDS producer/consumer -> no barrier
// (and __syncthreads would deadlock: divergent trip counts across waves).
__global__ __launch_bounds__(256) void k5_aggregate(const unsigned int* __restrict__ featb,
                             const float* __restrict__ el, const float* __restrict__ er,
                             const float* __restrict__ bias,
                             const int* __restrict__ offs, const int* __restrict__ csr,
                             float* __restrict__ z, int N, int E) {
    __shared__ float wbuf[4][64][HH];   // 4 KB
    int w = threadIdx.x >> 6, l = threadIdx.x & 63;
    int n = blockIdx.x * 4 + w;
    int p = blockIdx.y;
    if (n >= N) return;
    int hd = l >> 4;
    int c0 = 2 * l;
    const float* elp = el + (size_t)p * N * HH;
    const float* erp = er + (size_t)p * N * HH;
    float4 rv = *(const float4*)&erp[(size_t)n * HH];
    int j0 = offs[(size_t)p * (N + 1) + n];
    int j1 = offs[(size_t)p * (N + 1) + n + 1];
    const int* cs = csr + (size_t)p * E;
    const unsigned int* fp = featb + (size_t)p * N * 64;
    float acc0 = 0.f, acc1 = 0.f, sumw = 0.f;
    for (int base = j0; base < j1; base += 64) {
        int rem = j1 - base;
        int cnt = rem > 64 ? 64 : rem;
        int mysn = (l < cnt) ? cs[base + l] : 0;   // coalesced batch load of edge srcs
        float4 ev = *(const float4*)&elp[(size_t)mysn * HH];
        float4 wv;
        float e;
        e = ev.x + rv.x; e = fmaxf(e, NEG_SLOPE * e); wv.x = __expf(e);
        e = ev.y + rv.y; e = fmaxf(e, NEG_SLOPE * e); wv.y = __expf(e);
        e = ev.z + rv.z; e = fmaxf(e, NEG_SLOPE * e); wv.z = __expf(e);
        e = ev.w + rv.w; e = fmaxf(e, NEG_SLOPE * e); wv.w = __expf(e);
        *(float4*)&wbuf[w][l][0] = wv;
        // same-wave ds_write -> ds_read: hardware program order + lgkmcnt
        int tt = 0;
        for (; tt + 4 <= cnt; tt += 4) {
            int s0 = __shfl(mysn, tt);
            int s1 = __shfl(mysn, tt + 1);
            int s2 = __shfl(mysn, tt + 2);
            int s3 = __shfl(mysn, tt + 3);
            unsigned int v0 = fp[(size_t)s0 * 64 + l];
            unsigned int v1 = fp[(size_t)s1 * 64 + l];
            unsigned int v2 = fp[(size_t)s2 * 64 + l];
            unsigned int v3 = fp[(size_t)s3 * 64 + l];
            float w0 = wbuf[w][tt][hd];
            float w1 = wbuf[w][tt + 1][hd];
            float w2 = wbuf[w][tt + 2][hd];
            float w3 = wbuf[w][tt + 3][hd];
            acc0 = fmaf(w0, __uint_as_float(v0 << 16), acc0);
            acc1 = fmaf(w0, __uint_as_float(v0 & 0xFFFF0000u), acc1);
            acc0 = fmaf(w1, __uint_as_float(v1 << 16), acc0);
            acc1 = fmaf(w1, __uint_as_float(v1 & 0xFFFF0000u), acc1);
            acc0 = fmaf(w2, __uint_as_float(v2 << 16), acc0);
            acc1 = fmaf(w2, __uint_as_float(v2 & 0xFFFF0000u), acc1);
            acc0 = fmaf(w3, __uint_as_float(v3 << 16), acc0);
            acc1 = fmaf(w3, __uint_as_float(v3 & 0xFFFF0000u), acc1);
            sumw += (w0 + w1) + (w2 + w3);
        }
        for (; tt < cnt; ++tt) {
            int s0 = __shfl(mysn, tt);
            unsigned int v0 = fp[(size_t)s0 * 64 + l];
            float w0 = wbuf[w][tt][hd];
            acc0 = fmaf(w0, __uint_as_float(v0 << 16), acc0);
            acc1 = fmaf(w0, __uint_as_float(v0 & 0xFFFF0000u), acc1);
            sumw += w0;
        }
    }
    float inv = 1.f / sumw;   // self-loops guarantee sumw > 0
    float2 bv = *(const float2*)&bias[p * FF + c0];
    float z0 = acc0 * inv + bv.x;
    float z1 = acc1 * inv + bv.y;
    z0 = z0 > 0.f ? z0 : __expf(z0) - 1.f;
    z1 = z1 > 0.f ? z1 : __expf(z1) - 1.f;
    size_t zb = ((size_t)p * N + n) * FF;
    *(float2*)&z[zb + c0] = make_float2(z0, z1);
}

// K6: s[n,p] = tanh(z @ W1 + b1) @ W2; NB nodes/wave register tiling.
__global__ __launch_bounds__(256) void k6_semantic(const float* __restrict__ z, const float* __restrict__ W1,
                            const float* __restrict__ b1, const float* __restrict__ W2,
                            float* __restrict__ partials, int N) {
    __shared__ float wsum[4];
    int t = threadIdx.x;
    int l = t & 63;
    int wu = __builtin_amdgcn_readfirstlane(t >> 6);
    int p = blockIdx.y;
    int nbase = blockIdx.x * (4 * NB) + wu * NB;
    int c0 = 2 * l;
    float ssum = 0.f;
    if (nbase < N) {
        int maxoff = N - 1 - nbase;
        size_t roff[NB];
#pragma unroll
        for (int nn = 0; nn < NB; ++nn)
            roff[nn] = (size_t)(nn < maxoff ? nn : maxoff) * FF;
        const float* zb = z + ((size_t)p * N + nbase) * FF;
        float2 acc[NB];
#pragma unroll
        for (int i = 0; i < NB; ++i) acc[i] = make_float2(0.f, 0.f);
        for (int k = 0; k < FF; k += 4) {
            float2 wv0 = *(const float2*)&W1[(k + 0) * FF + c0];
            float2 wv1 = *(const float2*)&W1[(k + 1) * FF + c0];
            float2 wv2 = *(const float2*)&W1[(k + 2) * FF + c0];
            float2 wv3 = *(const float2*)&W1[(k + 3) * FF + c0];
#pragma unroll
            for (int nn = 0; nn < NB; ++nn) {
                float4 zv = *(const float4*)&zb[roff[nn] + k];   // wave-uniform -> s_load
                acc[nn].x = fmaf(zv.x, wv0.x, acc[nn].x);
                acc[nn].y = fmaf(zv.x, wv0.y, acc[nn].y);
                acc[nn].x = fmaf(zv.y, wv1.x, acc[nn].x);
                acc[nn].y = fmaf(zv.y, wv1.y, acc[nn].y);
                acc[nn].x = fmaf(zv.z, wv2.x, acc[nn].x);
                acc[nn].y = fmaf(zv.z, wv2.y, acc[nn].y);
                acc[nn].x = fmaf(zv.w, wv3.x, acc[nn].x);
                acc[nn].y = fmaf(zv.w, wv3.y, acc[nn].y);
            }
        }
        float2 b1v = *(const float2*)&b1[c0];
        float2 w2v = *(const float2*)&W2[c0];
#pragma unroll
        for (int nn = 0; nn < NB; ++nn) {
            bool valid = nn <= maxoff;
            float a0 = acc[nn].x + b1v.x;
            float a1 = acc[nn].y + b1v.y;
            // tanh(x) = 1 - 2/(exp(2x)+1)  (safe at +/-inf)
            float e0 = __expf(2.f * a0);
            float e1 = __expf(2.f * a1);
            float t0 = 1.f - 2.f * __builtin_amdgcn_rcpf(e0 + 1.f);
            float t1 = 1.f - 2.f * __builtin_amdgcn_rcpf(e1 + 1.f);
            ssum += valid ? (t0 * w2v.x + t1 * w2v.y) : 0.f;
        }
    }
    for (int off = 32; off >= 1; off >>= 1) ssum += __shfl_xor(ssum, off);
    if (l == 0) wsum[wu] = ssum;
    __syncthreads();
    if (t == 0)
        partials[(size_t)p * gridDim.x + blockIdx.x] = wsum[0] + wsum[1] + wsum[2] + wsum[3];
}

// K7: reduce partials -> w[p] mean -> beta softmax. one block, 3 waves.
__global__ void k7_beta(const float* __restrict__ partials, float* __restrict__ beta,
                        int nblk, int N) {
    __shared__ float wl[3];
    int p = threadIdx.x >> 6, l = threadIdx.x & 63;
    float s = 0.f;
    for (int i = l; i < nblk; i += 64) s += partials[(size_t)p * nblk + i];
    for (int off = 32; off >= 1; off >>= 1) s += __shfl_xor(s, off);
    if (l == 0) wl[p] = s / (float)N;
    __syncthreads();
    if (threadIdx.x == 0) {
        float m = fmaxf(wl[0], fmaxf(wl[1], wl[2]));
        float e0 = __expf(wl[0] - m), e1 = __expf(wl[1] - m), e2 = __expf(wl[2] - m);
        float inv = 1.f / (e0 + e1 + e2);
        beta[0] = e0 * inv; beta[1] = e1 * inv; beta[2] = e2 * inv;
    }
}

// K8: out[n,:] = sum_p beta[p] * z[p][n,:]
__global__ void k8_combine(const float* __restrict__ z, const float* __restrict__ beta,
                           float* __restrict__ out, int N) {
    size_t i = (size_t)blockIdx.x * 256 + threadIdx.x;
    size_t tot = (size_t)N * FF;
    if (i < tot) {
        float b0 = beta[0], b1 = beta[1], b2 = beta[2];
        out[i] = b0 * z[i] + b1 * z[tot + i] + b2 * z[2 * tot + i];
    }
}

extern "C" void kernel_launch(void* const* d_in, const int* in_sizes, int n_in,
                              void* d_out, int out_size, void* d_ws, size_t ws_size,
                              hipStream_t stream) {
    const float* h    = (const float*)d_in[0];
    const float* W    = (const float*)d_in[1];
    const float* al   = (const float*)d_in[2];
    const float* ar   = (const float*)d_in[3];
    const float* bias = (const float*)d_in[4];
    const float* W1   = (const float*)d_in[5];
    const float* b1   = (const float*)d_in[6];
    const float* W2   = (const float*)d_in[7];
    const int*   src  = (const int*)d_in[8];
    const int*   dst  = (const int*)d_in[9];
    float* out = (float*)d_out;

    int N = in_sizes[0] / INF_;
    int E = in_sizes[8] / PP;

    char* ws = (char*)d_ws;
    size_t off = 0;
    auto take = [&](size_t bytes) -> void* {
        off = (off + 255) & ~(size_t)255;
        void* ptr = ws + off;
        off += bytes;
        return ptr;
    };
    unsigned int* featb = (unsigned int*)take((size_t)PP * N * 64 * sizeof(unsigned int));
    float* z        = (float*)take((size_t)PP * N * FF * sizeof(float));
    float* el       = (float*)take((size_t)PP * N * HH * sizeof(float));
    float* er       = (float*)take((size_t)PP * N * HH * sizeof(float));
    int*   counts   = (int*)take((size_t)PP * N * sizeof(int));
    int*   offs     = (int*)take((size_t)PP * (N + 1) * sizeof(int));
    int*   cursor   = (int*)take((size_t)PP * N * sizeof(int));
    int*   csr      = (int*)take((size_t)PP * E * sizeof(int));
    int    nblk64   = (N + 4 * NB - 1) / (4 * NB);
    int    nblk4    = (N + 3) / 4;
    float* partials = (float*)take((size_t)PP * nblk64 * sizeof(float));
    float* betap    = (float*)take(16);
    (void)ws_size; (void)n_in; (void)out_size;

    hipMemsetAsync(counts, 0, (size_t)PP * N * sizeof(int), stream);

    dim3 gTile(nblk64, PP);
    dim3 gNode(nblk4, PP);
    dim3 gEdge((E + 255) / 256, PP);
    dim3 gScat(((E + K4CHUNK - 1) / K4CHUNK) * NPART, PP);

    k1_gemm<<<gTile, 256, 0, stream>>>(h, W, al, ar, featb, el, er, N);
    k2_hist<<<gEdge, 256, 0, stream>>>(dst, counts, E, N);
    k3_scan<<<PP, 1024, 0, stream>>>(counts, offs, cursor, N);
    k4_scatter<<<gScat, 256, 0, stream>>>(src, dst, cursor, csr, E, N);
    k5_aggregate<<<gNode, 256, 0, stream>>>(featb, el, er, bias, offs, csr, z, N, E);
    k6_semantic<<<gTile, 256, 0, stream>>>(z, W1, b1, W2, partials, N);
    k7_beta<<<1, 192, 0, stream>>>(partials, betap, nblk64, N);
    k8_combine<<<(int)(((size_t)N * FF + 255) / 256), 256, 0, stream>>>(z, betap, out, N);
}

// Round 7
// 696.256 us; speedup vs baseline: 1.2486x; 1.1493x over previous
//
#include <hip/hip_runtime.h>
#include <math.h>

#define PP 3
#define HH 4
#define DD 32
#define FF 128   // H*D
#define INF_ 128 // input feature dim
#define NEG_SLOPE 0.2f
#define NPART 8      // dst partitions ~ XCDs
#define K4CHUNK 8192 // edges per scatter block
#define NB 16        // nodes per wave in k6

typedef __bf16 bf16x8 __attribute__((ext_vector_type(8)));
typedef float f32x4 __attribute__((ext_vector_type(4)));

__device__ __forceinline__ unsigned int bf16pair(float x, float y) {
    unsigned int a = __float_as_uint(x);
    unsigned int b = __float_as_uint(y);
    a = (a + 0x7FFFu + ((a >> 16) & 1u)) >> 16;   // RNE round to bf16
    b = (b + 0x7FFFu + ((b >> 16) & 1u)) >> 16;
    return a | (b << 16);
}

// KH: h fp32 -> bf16 (once, shared by all paths)
__global__ __launch_bounds__(256) void kh_conv(const float* __restrict__ h,
                                               unsigned short* __restrict__ hb16,
                                               int total4) {
    int i = blockIdx.x * 256 + threadIdx.x;
    if (i < total4) {
        float4 v = *(const float4*)&h[(size_t)i * 4];
        unsigned int lo = bf16pair(v.x, v.y);
        unsigned int hi = bf16pair(v.z, v.w);
        *(uint2*)&hb16[(size_t)i * 4] = make_uint2(lo, hi);
    }
}

// KW: pack W into B-fragment order for mfma_f32_16x16x32_bf16:
// B[k][n] with n=lane&15, k=quad*8+j. Wpack[p][nt][ks][lane][j] (8 bf16 = 16B/lane).
__global__ __launch_bounds__(256) void kw_pack(const float* __restrict__ W,
                                               unsigned short* __restrict__ Wpack) {
    int idx = blockIdx.x * 256 + threadIdx.x;
    if (idx >= PP * 8 * 4 * 64) return;
    int lane = idx & 63;
    int ks = (idx >> 6) & 3;
    int nt = (idx >> 8) & 7;
    int p  = idx >> 11;
    int n  = nt * 16 + (lane & 15);
    int k0 = ks * 32 + (lane >> 4) * 8;
    const float* Wp = W + (size_t)p * INF_ * FF;
    unsigned int u0 = bf16pair(Wp[(k0 + 0) * FF + n], Wp[(k0 + 1) * FF + n]);
    unsigned int u1 = bf16pair(Wp[(k0 + 2) * FF + n], Wp[(k0 + 3) * FF + n]);
    unsigned int u2 = bf16pair(Wp[(k0 + 4) * FF + n], Wp[(k0 + 5) * FF + n]);
    unsigned int u3 = bf16pair(Wp[(k0 + 6) * FF + n], Wp[(k0 + 7) * FF + n]);
    *(uint4*)&Wpack[(size_t)idx * 8] = make_uint4(u0, u1, u2, u3);
}

// K1: feat[p] = h @ W[p] via bf16 MFMA. 4 waves/block; wave = 16 rows x 128 cols.
// D layout: col=lane&15, row=(lane>>4)*4+reg. el/er from fp32 acc via quad shuffles.
__global__ __launch_bounds__(256) void k1_mfma(const unsigned short* __restrict__ hb16,
                        const unsigned short* __restrict__ Wpack,
                        const float* __restrict__ al, const float* __restrict__ ar,
                        unsigned int* __restrict__ featb, float* __restrict__ el,
                        float* __restrict__ er, int N) {
    int l = threadIdx.x & 63;
    int wu = threadIdx.x >> 6;
    int p = blockIdx.y;
    int rowbase = blockIdx.x * 64 + wu * 16;
    if (rowbase >= N) return;
    int q = l >> 4;
    int t16 = l & 15;
    int arow = rowbase + t16; if (arow > N - 1) arow = N - 1;   // clamp tail loads
    const unsigned short* hrow = hb16 + (size_t)arow * INF_ + q * 8;
    const unsigned short* wp = Wpack + (size_t)p * 8 * 4 * 64 * 8;

    f32x4 acc[8];
#pragma unroll
    for (int i = 0; i < 8; ++i) acc[i] = (f32x4){0.f, 0.f, 0.f, 0.f};

#pragma unroll
    for (int ks = 0; ks < 4; ++ks) {
        bf16x8 av = *(const bf16x8*)&hrow[ks * 32];
#pragma unroll
        for (int nt = 0; nt < 8; ++nt) {
            bf16x8 bv = *(const bf16x8*)&wp[(((size_t)nt * 4 + ks) * 64 + l) * 8];
            acc[nt] = __builtin_amdgcn_mfma_f32_16x16x32_bf16(av, bv, acc[nt], 0, 0, 0);
        }
    }

    // el/er: col = nt*16 + t16, head = nt>>1
    float alv[8], arv[8];
#pragma unroll
    for (int nt = 0; nt < 8; ++nt) {
        int cc = (nt & 1) * 16 + t16;
        alv[nt] = al[((size_t)p * HH + (nt >> 1)) * DD + cc];
        arv[nt] = ar[((size_t)p * HH + (nt >> 1)) * DD + cc];
    }
    float elp[4][4], erp[4][4];
#pragma unroll
    for (int r = 0; r < 4; ++r)
#pragma unroll
        for (int hd = 0; hd < 4; ++hd) { elp[r][hd] = 0.f; erp[r][hd] = 0.f; }
#pragma unroll
    for (int nt = 0; nt < 8; ++nt)
#pragma unroll
        for (int r = 0; r < 4; ++r) {
            elp[r][nt >> 1] = fmaf(acc[nt][r], alv[nt], elp[r][nt >> 1]);
            erp[r][nt >> 1] = fmaf(acc[nt][r], arv[nt], erp[r][nt >> 1]);
        }
#pragma unroll
    for (int r = 0; r < 4; ++r)
#pragma unroll
        for (int hd = 0; hd < 4; ++hd) {
#pragma unroll
            for (int off = 8; off >= 1; off >>= 1) {
                elp[r][hd] += __shfl_xor(elp[r][hd], off);   // stays within 16-lane quad
                erp[r][hd] += __shfl_xor(erp[r][hd], off);
            }
        }

#pragma unroll
    for (int r = 0; r < 4; ++r) {
        int row = rowbase + q * 4 + r;
        bool vr = row < N;
        if (t16 == 0 && vr) {
#pragma unroll
            for (int hd = 0; hd < 4; ++hd) {
                el[((size_t)p * N + row) * HH + hd] = elp[r][hd];
                er[((size_t)p * N + row) * HH + hd] = erp[r][hd];
            }
        }
#pragma unroll
        for (int nt = 0; nt < 8; ++nt) {
            float partner = __shfl_xor(acc[nt][r], 1);   // col+1 for even lanes
            if ((l & 1) == 0 && vr) {
                int j = nt * 8 + (t16 >> 1);
                featb[((size_t)p * N + row) * 64 + j] = bf16pair(acc[nt][r], partner);
            }
        }
    }
}

// K2: histogram of dst degrees
__global__ void k2_hist(const int* __restrict__ dst, int* __restrict__ counts,
                        int E, int N) {
    int p = blockIdx.y;
    int i = blockIdx.x * 256 + threadIdx.x;
    if (i < E) atomicAdd(&counts[(size_t)p * N + dst[(size_t)p * E + i]], 1);
}

// K3: exclusive prefix sum over counts -> offs (N+1), cursor copy. one block per path.
__global__ __launch_bounds__(1024) void k3_scan(const int* __restrict__ counts,
                                                int* __restrict__ offs,
                                                int* __restrict__ cursor, int N) {
    __shared__ int lds[1024];
    int p = blockIdx.x;
    int t = threadIdx.x;
    int chunk = (N + 1023) / 1024;
    int base = t * chunk;
    int end = base + chunk; if (end > N) end = N; if (base > N) base = N;
    int s = 0;
    for (int i = base; i < end; ++i) s += counts[(size_t)p * N + i];
    lds[t] = s;
    __syncthreads();
    for (int off = 1; off < 1024; off <<= 1) {
        int v = (t >= off) ? lds[t - off] : 0;
        __syncthreads();
        lds[t] += v;
        __syncthreads();
    }
    int run = lds[t] - s;  // exclusive prefix for this thread
    for (int i = base; i < end; ++i) {
        offs[(size_t)p * (N + 1) + i] = run;
        cursor[(size_t)p * N + i] = run;
        run += counts[(size_t)p * N + i];
    }
    if (t == 0) offs[(size_t)p * (N + 1) + N] = lds[1023];
}

// K4: scatter src ids into CSR slots, dst-partitioned (stride-8 block
// families -> per-XCD L2 write combining). NO per-edge payload beyond the
// 4B src id: R4 showed scattered 16B writes cause RFO + 4x amplification.
__global__ __launch_bounds__(256) void k4_scatter(const int* __restrict__ src, const int* __restrict__ dst,
                           int* __restrict__ cursor, int* __restrict__ csr,
                           int E, int N) {
    int p = blockIdx.y;
    int part = blockIdx.x & (NPART - 1);
    int chunk = blockIdx.x >> 3;
    int pw = (N + NPART - 1) / NPART;
    int lo = part * pw;
    int hi = lo + pw; if (hi > N) hi = N;
    int base = chunk * K4CHUNK;
    int end = base + K4CHUNK; if (end > E) end = E;
    const int* sp = src + (size_t)p * E;
    const int* dp = dst + (size_t)p * E;
    int* cur = cursor + (size_t)p * N;
    int* cp = csr + (size_t)p * E;
    if ((E & 3) == 0) {
        for (int i = base + 4 * (int)threadIdx.x; i < end; i += 1024) {
            int4 d4 = *(const int4*)&dp[i];
            int4 s4 = *(const int4*)&sp[i];
            if (d4.x >= lo && d4.x < hi) cp[atomicAdd(&cur[d4.x], 1)] = s4.x;
            if (d4.y >= lo && d4.y < hi) cp[atomicAdd(&cur[d4.y], 1)] = s4.y;
            if (d4.z >= lo && d4.z < hi) cp[atomicAdd(&cur[d4.z], 1)] = s4.z;
            if (d4.w >= lo && d4.w < hi) cp[atomicAdd(&cur[d4.w], 1)] = s4.w;
        }
    } else {
        for (int i = base + (int)threadIdx.x; i < end; i += 256) {
            int d = dp[i];
            if (d >= lo && d < hi) cp[atomicAdd(&cur[d], 1)] = sp[i];
        }
    }
}

// K5: per-(node,path) single-pass softmax aggregation. Each lane computes all
// 4 head-exps for ITS one loaded edge, stashes to LDS; inner loop broadcasts
// via ds_read. Same-wave LDS producer/consumer -> no barrier needed.
__global__ __launch_bounds__(256) void k5_aggregate(const unsigned int* __restrict__ featb,
                             const float* __restrict__ el, const float* __restrict__ er,
                             const float* __restrict__ bias,
                             const int* __restrict__ offs, const int* __restrict__ csr,
                             float* __restrict__ z, int N, int E) {
    __shared__ float wbuf[4][64][HH];   // 4 KB
    int w = threadIdx.x >> 6, l = threadIdx.x & 63;
    int n = blockIdx.x * 4 + w;
    int p = blockIdx.y;
    if (n >= N) return;
    int hd = l >> 4;
    int c0 = 2 * l;
    const float* elp = el + (size_t)p * N * HH;
    const float* erp = er + (size_t)p * N * HH;
    float4 rv = *(const float4*)&erp[(size_t)n * HH];
    int j0 = offs[(size_t)p * (N + 1) + n];
    int j1 = offs[(size_t)p * (N + 1) + n + 1];
    const int* cs = csr + (size_t)p * E;
    const unsigned int* fp = featb + (size_t)p * N * 64;
    float acc0 = 0.f, acc1 = 0.f, sumw = 0.f;
    for (int base = j0; base < j1; base += 64) {
        int rem = j1 - base;
        int cnt = rem > 64 ? 64 : rem;
        int mysn = (l < cnt) ? cs[base + l] : 0;   // coalesced batch load of edge srcs
        float4 ev = *(const float4*)&elp[(size_t)mysn * HH];
        float4 wv;
        float e;
        e = ev.x + rv.x; e = fmaxf(e, NEG_SLOPE * e); wv.x = __expf(e);
        e = ev.y + rv.y; e = fmaxf(e, NEG_SLOPE * e); wv.y = __expf(e);
        e = ev.z + rv.z; e = fmaxf(e, NEG_SLOPE * e); wv.z = __expf(e);
        e = ev.w + rv.w; e = fmaxf(e, NEG_SLOPE * e); wv.w = __expf(e);
        *(float4*)&wbuf[w][l][0] = wv;
        int tt = 0;
        for (; tt + 4 <= cnt; tt += 4) {
            int s0 = __shfl(mysn, tt);
            int s1 = __shfl(mysn, tt + 1);
            int s2 = __shfl(mysn, tt + 2);
            int s3 = __shfl(mysn, tt + 3);
            unsigned int v0 = fp[(size_t)s0 * 64 + l];
            unsigned int v1 = fp[(size_t)s1 * 64 + l];
            unsigned int v2 = fp[(size_t)s2 * 64 + l];
            unsigned int v3 = fp[(size_t)s3 * 64 + l];
            float w0 = wbuf[w][tt][hd];
            float w1 = wbuf[w][tt + 1][hd];
            float w2 = wbuf[w][tt + 2][hd];
            float w3 = wbuf[w][tt + 3][hd];
            acc0 = fmaf(w0, __uint_as_float(v0 << 16), acc0);
            acc1 = fmaf(w0, __uint_as_float(v0 & 0xFFFF0000u), acc1);
            acc0 = fmaf(w1, __uint_as_float(v1 << 16), acc0);
            acc1 = fmaf(w1, __uint_as_float(v1 & 0xFFFF0000u), acc1);
            acc0 = fmaf(w2, __uint_as_float(v2 << 16), acc0);
            acc1 = fmaf(w2, __uint_as_float(v2 & 0xFFFF0000u), acc1);
            acc0 = fmaf(w3, __uint_as_float(v3 << 16), acc0);
            acc1 = fmaf(w3, __uint_as_float(v3 & 0xFFFF0000u), acc1);
            sumw += (w0 + w1) + (w2 + w3);
        }
        for (; tt < cnt; ++tt) {
            int s0 = __shfl(mysn, tt);
            unsigned int v0 = fp[(size_t)s0 * 64 + l];
            float w0 = wbuf[w][tt][hd];
            acc0 = fmaf(w0, __uint_as_float(v0 << 16), acc0);
            acc1 = fmaf(w0, __uint_as_float(v0 & 0xFFFF0000u), acc1);
            sumw += w0;
        }
    }
    float inv = 1.f / sumw;   // self-loops guarantee sumw > 0
    float2 bv = *(const float2*)&bias[p * FF + c0];
    float z0 = acc0 * inv + bv.x;
    float z1 = acc1 * inv + bv.y;
    z0 = z0 > 0.f ? z0 : __expf(z0) - 1.f;
    z1 = z1 > 0.f ? z1 : __expf(z1) - 1.f;
    size_t zb = ((size_t)p * N + n) * FF;
    *(float2*)&z[zb + c0] = make_float2(z0, z1);
}

// K6: s[n,p] = tanh(z @ W1 + b1) @ W2; NB nodes/wave register tiling.
__global__ __launch_bounds__(256) void k6_semantic(const float* __restrict__ z, const float* __restrict__ W1,
                            const float* __restrict__ b1, const float* __restrict__ W2,
                            float* __restrict__ partials, int N) {
    __shared__ float wsum[4];
    int t = threadIdx.x;
    int l = t & 63;
    int wu = __builtin_amdgcn_readfirstlane(t >> 6);
    int p = blockIdx.y;
    int nbase = blockIdx.x * (4 * NB) + wu * NB;
    int c0 = 2 * l;
    float ssum = 0.f;
    if (nbase < N) {
        int maxoff = N - 1 - nbase;
        size_t roff[NB];
#pragma unroll
        for (int nn = 0; nn < NB; ++nn)
            roff[nn] = (size_t)(nn < maxoff ? nn : maxoff) * FF;
        const float* zb = z + ((size_t)p * N + nbase) * FF;
        float2 acc[NB];
#pragma unroll
        for (int i = 0; i < NB; ++i) acc[i] = make_float2(0.f, 0.f);
        for (int k = 0; k < FF; k += 4) {
            float2 wv0 = *(const float2*)&W1[(k + 0) * FF + c0];
            float2 wv1 = *(const float2*)&W1[(k + 1) * FF + c0];
            float2 wv2 = *(const float2*)&W1[(k + 2) * FF + c0];
            float2 wv3 = *(const float2*)&W1[(k + 3) * FF + c0];
#pragma unroll
            for (int nn = 0; nn < NB; ++nn) {
                float4 zv = *(const float4*)&zb[roff[nn] + k];   // wave-uniform -> s_load
                acc[nn].x = fmaf(zv.x, wv0.x, acc[nn].x);
                acc[nn].y = fmaf(zv.x, wv0.y, acc[nn].y);
                acc[nn].x = fmaf(zv.y, wv1.x, acc[nn].x);
                acc[nn].y = fmaf(zv.y, wv1.y, acc[nn].y);
                acc[nn].x = fmaf(zv.z, wv2.x, acc[nn].x);
                acc[nn].y = fmaf(zv.z, wv2.y, acc[nn].y);
                acc[nn].x = fmaf(zv.w, wv3.x, acc[nn].x);
                acc[nn].y = fmaf(zv.w, wv3.y, acc[nn].y);
            }
        }
        float2 b1v = *(const float2*)&b1[c0];
        float2 w2v = *(const float2*)&W2[c0];
#pragma unroll
        for (int nn = 0; nn < NB; ++nn) {
            bool valid = nn <= maxoff;
            float a0 = acc[nn].x + b1v.x;
            float a1 = acc[nn].y + b1v.y;
            // tanh(x) = 1 - 2/(exp(2x)+1)  (safe at +/-inf)
            float e0 = __expf(2.f * a0);
            float e1 = __expf(2.f * a1);
            float t0 = 1.f - 2.f * __builtin_amdgcn_rcpf(e0 + 1.f);
            float t1 = 1.f - 2.f * __builtin_amdgcn_rcpf(e1 + 1.f);
            ssum += valid ? (t0 * w2v.x + t1 * w2v.y) : 0.f;
        }
    }
    for (int off = 32; off >= 1; off >>= 1) ssum += __shfl_xor(ssum, off);
    if (l == 0) wsum[wu] = ssum;
    __syncthreads();
    if (t == 0)
        partials[(size_t)p * gridDim.x + blockIdx.x] = wsum[0] + wsum[1] + wsum[2] + wsum[3];
}

// K7: reduce partials -> w[p] mean -> beta softmax. one block, 3 waves.
__global__ void k7_beta(const float* __restrict__ partials, float* __restrict__ beta,
                        int nblk, int N) {
    __shared__ float wl[3];
    int p = threadIdx.x >> 6, l = threadIdx.x & 63;
    float s = 0.f;
    for (int i = l; i < nblk; i += 64) s += partials[(size_t)p * nblk + i];
    for (int off = 32; off >= 1; off >>= 1) s += __shfl_xor(s, off);
    if (l == 0) wl[p] = s / (float)N;
    __syncthreads();
    if (threadIdx.x == 0) {
        float m = fmaxf(wl[0], fmaxf(wl[1], wl[2]));
        float e0 = __expf(wl[0] - m), e1 = __expf(wl[1] - m), e2 = __expf(wl[2] - m);
        float inv = 1.f / (e0 + e1 + e2);
        beta[0] = e0 * inv; beta[1] = e1 * inv; beta[2] = e2 * inv;
    }
}

// K8: out[n,:] = sum_p beta[p] * z[p][n,:]
__global__ void k8_combine(const float* __restrict__ z, const float* __restrict__ beta,
                           float* __restrict__ out, int N) {
    size_t i = (size_t)blockIdx.x * 256 + threadIdx.x;
    size_t tot = (size_t)N * FF;
    if (i < tot) {
        float b0 = beta[0], b1 = beta[1], b2 = beta[2];
        out[i] = b0 * z[i] + b1 * z[tot + i] + b2 * z[2 * tot + i];
    }
}

extern "C" void kernel_launch(void* const* d_in, const int* in_sizes, int n_in,
                              void* d_out, int out_size, void* d_ws, size_t ws_size,
                              hipStream_t stream) {
    const float* h    = (const float*)d_in[0];
    const float* W    = (const float*)d_in[1];
    const float* al   = (const float*)d_in[2];
    const float* ar   = (const float*)d_in[3];
    const float* bias = (const float*)d_in[4];
    const float* W1   = (const float*)d_in[5];
    const float* b1   = (const float*)d_in[6];
    const float* W2   = (const float*)d_in[7];
    const int*   src  = (const int*)d_in[8];
    const int*   dst  = (const int*)d_in[9];
    float* out = (float*)d_out;

    int N = in_sizes[0] / INF_;
    int E = in_sizes[8] / PP;

    char* ws = (char*)d_ws;
    size_t off = 0;
    auto take = [&](size_t bytes) -> void* {
        off = (off + 255) & ~(size_t)255;
        void* ptr = ws + off;
        off += bytes;
        return ptr;
    };
    unsigned int* featb = (unsigned int*)take((size_t)PP * N * 64 * sizeof(unsigned int));
    float* z        = (float*)take((size_t)PP * N * FF * sizeof(float));
    float* el       = (float*)take((size_t)PP * N * HH * sizeof(float));
    float* er       = (float*)take((size_t)PP * N * HH * sizeof(float));
    int*   counts   = (int*)take((size_t)PP * N * sizeof(int));
    int*   offs     = (int*)take((size_t)PP * (N + 1) * sizeof(int));
    int*   cursor   = (int*)take((size_t)PP * N * sizeof(int));
    int*   csr      = (int*)take((size_t)PP * E * sizeof(int));
    unsigned short* hb16  = (unsigned short*)take((size_t)N * INF_ * sizeof(unsigned short));
    unsigned short* Wpack = (unsigned short*)take((size_t)PP * 8 * 4 * 64 * 8 * sizeof(unsigned short));
    int    nblk64   = (N + 4 * NB - 1) / (4 * NB);
    int    nblk4    = (N + 3) / 4;
    float* partials = (float*)take((size_t)PP * nblk64 * sizeof(float));
    float* betap    = (float*)take(16);
    (void)ws_size; (void)n_in; (void)out_size;

    hipMemsetAsync(counts, 0, (size_t)PP * N * sizeof(int), stream);

    int total4 = N * INF_ / 4;
    dim3 gM((N + 63) / 64, PP);
    dim3 gTile(nblk64, PP);
    dim3 gNode(nblk4, PP);
    dim3 gEdge((E + 255) / 256, PP);
    dim3 gScat(((E + K4CHUNK - 1) / K4CHUNK) * NPART, PP);

    kh_conv<<<(total4 + 255) / 256, 256, 0, stream>>>(h, hb16, total4);
    kw_pack<<<(PP * 8 * 4 * 64 + 255) / 256, 256, 0, stream>>>(W, Wpack);
    k1_mfma<<<gM, 256, 0, stream>>>(hb16, Wpack, al, ar, featb, el, er, N);
    k2_hist<<<gEdge, 256, 0, stream>>>(dst, counts, E, N);
    k3_scan<<<PP, 1024, 0, stream>>>(counts, offs, cursor, N);
    k4_scatter<<<gScat, 256, 0, stream>>>(src, dst, cursor, csr, E, N);
    k5_aggregate<<<gNode, 256, 0, stream>>>(featb, el, er, bias, offs, csr, z, N, E);
    k6_semantic<<<gTile, 256, 0, stream>>>(z, W1, b1, W2, partials, N);
    k7_beta<<<1, 192, 0, stream>>>(partials, betap, nblk64, N);
    k8_combine<<<(int)(((size_t)N * FF + 255) / 256), 256, 0, stream>>>(z, betap, out, N);
}

// Round 8
// 593.241 us; speedup vs baseline: 1.4654x; 1.1736x over previous
//
#include <hip/hip_runtime.h>
#include <math.h>

#define PP 3
#define HH 4
#define DD 32
#define FF 128   // H*D
#define INF_ 128 // input feature dim
#define NEG_SLOPE 0.2f
#define NPART 8      // dst partitions ~ XCDs
#define K4CHUNK 8192 // edges per scatter block

typedef __bf16 bf16x8 __attribute__((ext_vector_type(8)));
typedef float f32x4 __attribute__((ext_vector_type(4)));

__device__ __forceinline__ unsigned int bf16pair(float x, float y) {
    unsigned int a = __float_as_uint(x);
    unsigned int b = __float_as_uint(y);
    a = (a + 0x7FFFu + ((a >> 16) & 1u)) >> 16;   // RNE round to bf16
    b = (b + 0x7FFFu + ((b >> 16) & 1u)) >> 16;
    return a | (b << 16);
}

// KH: h fp32 -> bf16 (once, shared by all paths)
__global__ __launch_bounds__(256) void kh_conv(const float* __restrict__ h,
                                               unsigned short* __restrict__ hb16,
                                               int total4) {
    int i = blockIdx.x * 256 + threadIdx.x;
    if (i < total4) {
        float4 v = *(const float4*)&h[(size_t)i * 4];
        unsigned int lo = bf16pair(v.x, v.y);
        unsigned int hi = bf16pair(v.z, v.w);
        *(uint2*)&hb16[(size_t)i * 4] = make_uint2(lo, hi);
    }
}

// KW: pack nmat 128x128 fp32 matrices into B-fragment order for
// mfma_f32_16x16x32_bf16: B[k][n], n=lane&15, k=quad*8+j.
// Wpack[m][nt][ks][lane][j] (8 bf16 = 16B/lane).
__global__ __launch_bounds__(256) void kw_pack(const float* __restrict__ W,
                                               unsigned short* __restrict__ Wpack,
                                               int nmat) {
    int idx = blockIdx.x * 256 + threadIdx.x;
    if (idx >= nmat * 8 * 4 * 64) return;
    int lane = idx & 63;
    int ks = (idx >> 6) & 3;
    int nt = (idx >> 8) & 7;
    int m  = idx >> 11;
    int n  = nt * 16 + (lane & 15);
    int k0 = ks * 32 + (lane >> 4) * 8;
    const float* Wp = W + (size_t)m * INF_ * FF;
    unsigned int u0 = bf16pair(Wp[(k0 + 0) * FF + n], Wp[(k0 + 1) * FF + n]);
    unsigned int u1 = bf16pair(Wp[(k0 + 2) * FF + n], Wp[(k0 + 3) * FF + n]);
    unsigned int u2 = bf16pair(Wp[(k0 + 4) * FF + n], Wp[(k0 + 5) * FF + n]);
    unsigned int u3 = bf16pair(Wp[(k0 + 6) * FF + n], Wp[(k0 + 7) * FF + n]);
    *(uint4*)&Wpack[(size_t)idx * 8] = make_uint4(u0, u1, u2, u3);
}

// K1: feat[p] = h @ W[p] via bf16 MFMA. 4 waves/block; wave = 16 rows x 128 cols.
// D layout: col=lane&15, row=(lane>>4)*4+reg. el/er from fp32 acc via quad shuffles.
__global__ __launch_bounds__(256) void k1_mfma(const unsigned short* __restrict__ hb16,
                        const unsigned short* __restrict__ Wpack,
                        const float* __restrict__ al, const float* __restrict__ ar,
                        unsigned int* __restrict__ featb, float* __restrict__ el,
                        float* __restrict__ er, int N) {
    int l = threadIdx.x & 63;
    int wu = threadIdx.x >> 6;
    int p = blockIdx.y;
    int rowbase = blockIdx.x * 64 + wu * 16;
    if (rowbase >= N) return;
    int q = l >> 4;
    int t16 = l & 15;
    int arow = rowbase + t16; if (arow > N - 1) arow = N - 1;   // clamp tail loads
    const unsigned short* hrow = hb16 + (size_t)arow * INF_ + q * 8;
    const unsigned short* wp = Wpack + (size_t)p * 8 * 4 * 64 * 8;

    f32x4 acc[8];
#pragma unroll
    for (int i = 0; i < 8; ++i) acc[i] = (f32x4){0.f, 0.f, 0.f, 0.f};

#pragma unroll
    for (int ks = 0; ks < 4; ++ks) {
        bf16x8 av = *(const bf16x8*)&hrow[ks * 32];
#pragma unroll
        for (int nt = 0; nt < 8; ++nt) {
            bf16x8 bv = *(const bf16x8*)&wp[(((size_t)nt * 4 + ks) * 64 + l) * 8];
            acc[nt] = __builtin_amdgcn_mfma_f32_16x16x32_bf16(av, bv, acc[nt], 0, 0, 0);
        }
    }

    // el/er: col = nt*16 + t16, head = nt>>1
    float alv[8], arv[8];
#pragma unroll
    for (int nt = 0; nt < 8; ++nt) {
        int cc = (nt & 1) * 16 + t16;
        alv[nt] = al[((size_t)p * HH + (nt >> 1)) * DD + cc];
        arv[nt] = ar[((size_t)p * HH + (nt >> 1)) * DD + cc];
    }
    float elp[4][4], erp[4][4];
#pragma unroll
    for (int r = 0; r < 4; ++r)
#pragma unroll
        for (int hd = 0; hd < 4; ++hd) { elp[r][hd] = 0.f; erp[r][hd] = 0.f; }
#pragma unroll
    for (int nt = 0; nt < 8; ++nt)
#pragma unroll
        for (int r = 0; r < 4; ++r) {
            elp[r][nt >> 1] = fmaf(acc[nt][r], alv[nt], elp[r][nt >> 1]);
            erp[r][nt >> 1] = fmaf(acc[nt][r], arv[nt], erp[r][nt >> 1]);
        }
#pragma unroll
    for (int r = 0; r < 4; ++r)
#pragma unroll
        for (int hd = 0; hd < 4; ++hd) {
#pragma unroll
            for (int off = 8; off >= 1; off >>= 1) {
                elp[r][hd] += __shfl_xor(elp[r][hd], off);   // stays within 16-lane quad
                erp[r][hd] += __shfl_xor(erp[r][hd], off);
            }
        }

#pragma unroll
    for (int r = 0; r < 4; ++r) {
        int row = rowbase + q * 4 + r;
        bool vr = row < N;
        if (t16 == 0 && vr) {
#pragma unroll
            for (int hd = 0; hd < 4; ++hd) {
                el[((size_t)p * N + row) * HH + hd] = elp[r][hd];
                er[((size_t)p * N + row) * HH + hd] = erp[r][hd];
            }
        }
#pragma unroll
        for (int nt = 0; nt < 8; ++nt) {
            float partner = __shfl_xor(acc[nt][r], 1);   // col+1 for even lanes
            if ((l & 1) == 0 && vr) {
                int j = nt * 8 + (t16 >> 1);
                featb[((size_t)p * N + row) * 64 + j] = bf16pair(acc[nt][r], partner);
            }
        }
    }
}

// K2: histogram of dst degrees
__global__ void k2_hist(const int* __restrict__ dst, int* __restrict__ counts,
                        int E, int N) {
    int p = blockIdx.y;
    int i = blockIdx.x * 256 + threadIdx.x;
    if (i < E) atomicAdd(&counts[(size_t)p * N + dst[(size_t)p * E + i]], 1);
}

// K3: exclusive prefix sum over counts -> offs (N+1), cursor copy. one block per path.
__global__ __launch_bounds__(1024) void k3_scan(const int* __restrict__ counts,
                                                int* __restrict__ offs,
                                                int* __restrict__ cursor, int N) {
    __shared__ int lds[1024];
    int p = blockIdx.x;
    int t = threadIdx.x;
    int chunk = (N + 1023) / 1024;
    int base = t * chunk;
    int end = base + chunk; if (end > N) end = N; if (base > N) base = N;
    int s = 0;
    for (int i = base; i < end; ++i) s += counts[(size_t)p * N + i];
    lds[t] = s;
    __syncthreads();
    for (int off = 1; off < 1024; off <<= 1) {
        int v = (t >= off) ? lds[t - off] : 0;
        __syncthreads();
        lds[t] += v;
        __syncthreads();
    }
    int run = lds[t] - s;  // exclusive prefix for this thread
    for (int i = base; i < end; ++i) {
        offs[(size_t)p * (N + 1) + i] = run;
        cursor[(size_t)p * N + i] = run;
        run += counts[(size_t)p * N + i];
    }
    if (t == 0) offs[(size_t)p * (N + 1) + N] = lds[1023];
}

// K4: scatter src ids into CSR slots, dst-partitioned (stride-8 block
// families -> per-XCD L2 write combining). NO per-edge payload beyond the
// 4B src id: R4 showed scattered 16B writes cause RFO + 4x amplification.
__global__ __launch_bounds__(256) void k4_scatter(const int* __restrict__ src, const int* __restrict__ dst,
                           int* __restrict__ cursor, int* __restrict__ csr,
                           int E, int N) {
    int p = blockIdx.y;
    int part = blockIdx.x & (NPART - 1);
    int chunk = blockIdx.x >> 3;
    int pw = (N + NPART - 1) / NPART;
    int lo = part * pw;
    int hi = lo + pw; if (hi > N) hi = N;
    int base = chunk * K4CHUNK;
    int end = base + K4CHUNK; if (end > E) end = E;
    const int* sp = src + (size_t)p * E;
    const int* dp = dst + (size_t)p * E;
    int* cur = cursor + (size_t)p * N;
    int* cp = csr + (size_t)p * E;
    if ((E & 3) == 0) {
        for (int i = base + 4 * (int)threadIdx.x; i < end; i += 1024) {
            int4 d4 = *(const int4*)&dp[i];
            int4 s4 = *(const int4*)&sp[i];
            if (d4.x >= lo && d4.x < hi) cp[atomicAdd(&cur[d4.x], 1)] = s4.x;
            if (d4.y >= lo && d4.y < hi) cp[atomicAdd(&cur[d4.y], 1)] = s4.y;
            if (d4.z >= lo && d4.z < hi) cp[atomicAdd(&cur[d4.z], 1)] = s4.z;
            if (d4.w >= lo && d4.w < hi) cp[atomicAdd(&cur[d4.w], 1)] = s4.w;
        }
    } else {
        for (int i = base + (int)threadIdx.x; i < end; i += 256) {
            int d = dp[i];
            if (d >= lo && d < hi) cp[atomicAdd(&cur[d], 1)] = sp[i];
        }
    }
}

// K5: per-(node,path) single-pass softmax aggregation. Each lane computes all
// 4 head-exps for ITS one loaded edge, stashes to LDS; inner loop broadcasts
// via ds_read. Same-wave LDS producer/consumer -> no barrier needed.
// Emits z fp32 (for k8 output path) AND packed bf16 (for k6 MFMA).
__global__ __launch_bounds__(256) void k5_aggregate(const unsigned int* __restrict__ featb,
                             const float* __restrict__ el, const float* __restrict__ er,
                             const float* __restrict__ bias,
                             const int* __restrict__ offs, const int* __restrict__ csr,
                             float* __restrict__ z, unsigned int* __restrict__ zb16,
                             int N, int E) {
    __shared__ float wbuf[4][64][HH];   // 4 KB
    int w = threadIdx.x >> 6, l = threadIdx.x & 63;
    int n = blockIdx.x * 4 + w;
    int p = blockIdx.y;
    if (n >= N) return;
    int hd = l >> 4;
    int c0 = 2 * l;
    const float* elp = el + (size_t)p * N * HH;
    const float* erp = er + (size_t)p * N * HH;
    float4 rv = *(const float4*)&erp[(size_t)n * HH];
    int j0 = offs[(size_t)p * (N + 1) + n];
    int j1 = offs[(size_t)p * (N + 1) + n + 1];
    const int* cs = csr + (size_t)p * E;
    const unsigned int* fp = featb + (size_t)p * N * 64;
    float acc0 = 0.f, acc1 = 0.f, sumw = 0.f;
    for (int base = j0; base < j1; base += 64) {
        int rem = j1 - base;
        int cnt = rem > 64 ? 64 : rem;
        int mysn = (l < cnt) ? cs[base + l] : 0;   // coalesced batch load of edge srcs
        float4 ev = *(const float4*)&elp[(size_t)mysn * HH];
        float4 wv;
        float e;
        e = ev.x + rv.x; e = fmaxf(e, NEG_SLOPE * e); wv.x = __expf(e);
        e = ev.y + rv.y; e = fmaxf(e, NEG_SLOPE * e); wv.y = __expf(e);
        e = ev.z + rv.z; e = fmaxf(e, NEG_SLOPE * e); wv.z = __expf(e);
        e = ev.w + rv.w; e = fmaxf(e, NEG_SLOPE * e); wv.w = __expf(e);
        *(float4*)&wbuf[w][l][0] = wv;
        int tt = 0;
        for (; tt + 4 <= cnt; tt += 4) {
            int s0 = __shfl(mysn, tt);
            int s1 = __shfl(mysn, tt + 1);
            int s2 = __shfl(mysn, tt + 2);
            int s3 = __shfl(mysn, tt + 3);
            unsigned int v0 = fp[(size_t)s0 * 64 + l];
            unsigned int v1 = fp[(size_t)s1 * 64 + l];
            unsigned int v2 = fp[(size_t)s2 * 64 + l];
            unsigned int v3 = fp[(size_t)s3 * 64 + l];
            float w0 = wbuf[w][tt][hd];
            float w1 = wbuf[w][tt + 1][hd];
            float w2 = wbuf[w][tt + 2][hd];
            float w3 = wbuf[w][tt + 3][hd];
            acc0 = fmaf(w0, __uint_as_float(v0 << 16), acc0);
            acc1 = fmaf(w0, __uint_as_float(v0 & 0xFFFF0000u), acc1);
            acc0 = fmaf(w1, __uint_as_float(v1 << 16), acc0);
            acc1 = fmaf(w1, __uint_as_float(v1 & 0xFFFF0000u), acc1);
            acc0 = fmaf(w2, __uint_as_float(v2 << 16), acc0);
            acc1 = fmaf(w2, __uint_as_float(v2 & 0xFFFF0000u), acc1);
            acc0 = fmaf(w3, __uint_as_float(v3 << 16), acc0);
            acc1 = fmaf(w3, __uint_as_float(v3 & 0xFFFF0000u), acc1);
            sumw += (w0 + w1) + (w2 + w3);
        }
        for (; tt < cnt; ++tt) {
            int s0 = __shfl(mysn, tt);
            unsigned int v0 = fp[(size_t)s0 * 64 + l];
            float w0 = wbuf[w][tt][hd];
            acc0 = fmaf(w0, __uint_as_float(v0 << 16), acc0);
            acc1 = fmaf(w0, __uint_as_float(v0 & 0xFFFF0000u), acc1);
            sumw += w0;
        }
    }
    float inv = 1.f / sumw;   // self-loops guarantee sumw > 0
    float2 bv = *(const float2*)&bias[p * FF + c0];
    float z0 = acc0 * inv + bv.x;
    float z1 = acc1 * inv + bv.y;
    z0 = z0 > 0.f ? z0 : __expf(z0) - 1.f;
    z1 = z1 > 0.f ? z1 : __expf(z1) - 1.f;
    size_t zb = ((size_t)p * N + n) * FF;
    *(float2*)&z[zb + c0] = make_float2(z0, z1);
    zb16[((size_t)p * N + n) * 64 + l] = bf16pair(z0, z1);
}

// K6: s[n,p] = tanh(z @ W1 + b1) @ W2 via bf16 MFMA, summed over n per block.
// Same wave structure as k1: 16 rows x 128 cols, D col=nt*16+t16, row=q*4+r.
__global__ __launch_bounds__(256) void k6_mfma(const unsigned int* __restrict__ zb16,
                        const unsigned short* __restrict__ W1pack,
                        const float* __restrict__ b1, const float* __restrict__ W2,
                        float* __restrict__ partials, int N) {
    __shared__ float wsum[4];
    int l = threadIdx.x & 63;
    int wu = threadIdx.x >> 6;
    int p = blockIdx.y;
    int rowbase = blockIdx.x * 64 + wu * 16;
    float ssum = 0.f;
    if (rowbase < N) {
        int q = l >> 4;
        int t16 = l & 15;
        int arow = rowbase + t16; if (arow > N - 1) arow = N - 1;
        const unsigned short* zrow =
            (const unsigned short*)(zb16 + ((size_t)p * N + arow) * 64) + q * 8;

        f32x4 acc[8];
#pragma unroll
        for (int i = 0; i < 8; ++i) acc[i] = (f32x4){0.f, 0.f, 0.f, 0.f};
#pragma unroll
        for (int ks = 0; ks < 4; ++ks) {
            bf16x8 av = *(const bf16x8*)&zrow[ks * 32];
#pragma unroll
            for (int nt = 0; nt < 8; ++nt) {
                bf16x8 bv = *(const bf16x8*)&W1pack[(((size_t)nt * 4 + ks) * 64 + l) * 8];
                acc[nt] = __builtin_amdgcn_mfma_f32_16x16x32_bf16(av, bv, acc[nt], 0, 0, 0);
            }
        }
        float b1v[8], w2v[8];
#pragma unroll
        for (int nt = 0; nt < 8; ++nt) {
            int col = nt * 16 + t16;
            b1v[nt] = b1[col];
            w2v[nt] = W2[col];
        }
        float rowsum[4] = {0.f, 0.f, 0.f, 0.f};
#pragma unroll
        for (int nt = 0; nt < 8; ++nt)
#pragma unroll
            for (int r = 0; r < 4; ++r) {
                float a = acc[nt][r] + b1v[nt];
                float e = __expf(2.f * a);
                float t = 1.f - 2.f * __builtin_amdgcn_rcpf(e + 1.f);
                rowsum[r] = fmaf(t, w2v[nt], rowsum[r]);
            }
#pragma unroll
        for (int r = 0; r < 4; ++r) {
            int row = rowbase + q * 4 + r;
            ssum += (row < N) ? rowsum[r] : 0.f;
        }
#pragma unroll
        for (int off = 32; off >= 1; off >>= 1) ssum += __shfl_xor(ssum, off);
    }
    if (l == 0) wsum[wu] = ssum;
    __syncthreads();
    if (threadIdx.x == 0)
        partials[(size_t)p * gridDim.x + blockIdx.x] = wsum[0] + wsum[1] + wsum[2] + wsum[3];
}

// K7: reduce partials -> w[p] mean -> beta softmax. one block, 3 waves.
__global__ void k7_beta(const float* __restrict__ partials, float* __restrict__ beta,
                        int nblk, int N) {
    __shared__ float wl[3];
    int p = threadIdx.x >> 6, l = threadIdx.x & 63;
    float s = 0.f;
    for (int i = l; i < nblk; i += 64) s += partials[(size_t)p * nblk + i];
    for (int off = 32; off >= 1; off >>= 1) s += __shfl_xor(s, off);
    if (l == 0) wl[p] = s / (float)N;
    __syncthreads();
    if (threadIdx.x == 0) {
        float m = fmaxf(wl[0], fmaxf(wl[1], wl[2]));
        float e0 = __expf(wl[0] - m), e1 = __expf(wl[1] - m), e2 = __expf(wl[2] - m);
        float inv = 1.f / (e0 + e1 + e2);
        beta[0] = e0 * inv; beta[1] = e1 * inv; beta[2] = e2 * inv;
    }
}

// K8: out[n,:] = sum_p beta[p] * z[p][n,:]  (fp32 z path — precision preserved)
__global__ void k8_combine(const float* __restrict__ z, const float* __restrict__ beta,
                           float* __restrict__ out, int N) {
    size_t i = (size_t)blockIdx.x * 256 + threadIdx.x;
    size_t tot = (size_t)N * FF;
    if (i < tot) {
        float b0 = beta[0], b1 = beta[1], b2 = beta[2];
        out[i] = b0 * z[i] + b1 * z[tot + i] + b2 * z[2 * tot + i];
    }
}

extern "C" void kernel_launch(void* const* d_in, const int* in_sizes, int n_in,
                              void* d_out, int out_size, void* d_ws, size_t ws_size,
                              hipStream_t stream) {
    const float* h    = (const float*)d_in[0];
    const float* W    = (const float*)d_in[1];
    const float* al   = (const float*)d_in[2];
    const float* ar   = (const float*)d_in[3];
    const float* bias = (const float*)d_in[4];
    const float* W1   = (const float*)d_in[5];
    const float* b1   = (const float*)d_in[6];
    const float* W2   = (const float*)d_in[7];
    const int*   src  = (const int*)d_in[8];
    const int*   dst  = (const int*)d_in[9];
    float* out = (float*)d_out;

    int N = in_sizes[0] / INF_;
    int E = in_sizes[8] / PP;

    char* ws = (char*)d_ws;
    size_t off = 0;
    auto take = [&](size_t bytes) -> void* {
        off = (off + 255) & ~(size_t)255;
        void* ptr = ws + off;
        off += bytes;
        return ptr;
    };
    unsigned int* featb = (unsigned int*)take((size_t)PP * N * 64 * sizeof(unsigned int));
    float* z        = (float*)take((size_t)PP * N * FF * sizeof(float));
    unsigned int* zb16 = (unsigned int*)take((size_t)PP * N * 64 * sizeof(unsigned int));
    float* el       = (float*)take((size_t)PP * N * HH * sizeof(float));
    float* er       = (float*)take((size_t)PP * N * HH * sizeof(float));
    int*   counts   = (int*)take((size_t)PP * N * sizeof(int));
    int*   offs     = (int*)take((size_t)PP * (N + 1) * sizeof(int));
    int*   cursor   = (int*)take((size_t)PP * N * sizeof(int));
    int*   csr      = (int*)take((size_t)PP * E * sizeof(int));
    unsigned short* hb16   = (unsigned short*)take((size_t)N * INF_ * sizeof(unsigned short));
    unsigned short* Wpack  = (unsigned short*)take((size_t)PP * 8 * 4 * 64 * 8 * sizeof(unsigned short));
    unsigned short* W1pack = (unsigned short*)take((size_t)8 * 4 * 64 * 8 * sizeof(unsigned short));
    int    nblkM    = (N + 63) / 64;
    int    nblk4    = (N + 3) / 4;
    float* partials = (float*)take((size_t)PP * nblkM * sizeof(float));
    float* betap    = (float*)take(16);
    (void)ws_size; (void)n_in; (void)out_size;

    hipMemsetAsync(counts, 0, (size_t)PP * N * sizeof(int), stream);

    int total4 = N * INF_ / 4;
    dim3 gM(nblkM, PP);
    dim3 gNode(nblk4, PP);
    dim3 gEdge((E + 255) / 256, PP);
    dim3 gScat(((E + K4CHUNK - 1) / K4CHUNK) * NPART, PP);

    kh_conv<<<(total4 + 255) / 256, 256, 0, stream>>>(h, hb16, total4);
    kw_pack<<<(PP * 2048 + 255) / 256, 256, 0, stream>>>(W, Wpack, PP);
    kw_pack<<<(2048 + 255) / 256, 256, 0, stream>>>(W1, W1pack, 1);
    k1_mfma<<<gM, 256, 0, stream>>>(hb16, Wpack, al, ar, featb, el, er, N);
    k2_hist<<<gEdge, 256, 0, stream>>>(dst, counts, E, N);
    k3_scan<<<PP, 1024, 0, stream>>>(counts, offs, cursor, N);
    k4_scatter<<<gScat, 256, 0, stream>>>(src, dst, cursor, csr, E, N);
    k5_aggregate<<<gNode, 256, 0, stream>>>(featb, el, er, bias, offs, csr, z, zb16, N, E);
    k6_mfma<<<gM, 256, 0, stream>>>(zb16, W1pack, b1, W2, partials, N);
    k7_beta<<<1, 192, 0, stream>>>(partials, betap, nblkM, N);
    k8_combine<<<(int)(((size_t)N * FF + 255) / 256), 256, 0, stream>>>(z, betap, out, N);
}

// Round 9
// 318.966 us; speedup vs baseline: 2.7256x; 1.8599x over previous
//
#include <hip/hip_runtime.h>
#include <math.h>

#define PP 3
#define HH 4
#define DD 32
#define FF 128   // H*D
#define INF_ 128 // input feature dim
#define NEG_SLOPE 0.2f

#define BSHIFT 9          // bucket = dst >> 9  (512 nodes/bucket)
#define BW 512            // nodes per bucket
#define BCAP 10240        // max edges per bucket (mean ~8700, sigma ~90 -> 17 sigma)
#define ACH 8             // edge rounds per thread in kA (chunk = 2048 edges)

typedef __bf16 bf16x8 __attribute__((ext_vector_type(8)));
typedef float f32x4 __attribute__((ext_vector_type(4)));

__device__ __forceinline__ unsigned int bf16pair(float x, float y) {
    unsigned int a = __float_as_uint(x);
    unsigned int b = __float_as_uint(y);
    a = (a + 0x7FFFu + ((a >> 16) & 1u)) >> 16;   // RNE round to bf16
    b = (b + 0x7FFFu + ((b >> 16) & 1u)) >> 16;
    return a | (b << 16);
}

// KH: h fp32 -> bf16 (once, shared by all paths)
__global__ __launch_bounds__(256) void kh_conv(const float* __restrict__ h,
                                               unsigned short* __restrict__ hb16,
                                               int total4) {
    int i = blockIdx.x * 256 + threadIdx.x;
    if (i < total4) {
        float4 v = *(const float4*)&h[(size_t)i * 4];
        unsigned int lo = bf16pair(v.x, v.y);
        unsigned int hi = bf16pair(v.z, v.w);
        *(uint2*)&hb16[(size_t)i * 4] = make_uint2(lo, hi);
    }
}

// KW: pack nmat 128x128 fp32 matrices into B-fragment order for
// mfma_f32_16x16x32_bf16: B[k][n], n=lane&15, k=quad*8+j.
__global__ __launch_bounds__(256) void kw_pack(const float* __restrict__ W,
                                               unsigned short* __restrict__ Wpack,
                                               int nmat) {
    int idx = blockIdx.x * 256 + threadIdx.x;
    if (idx >= nmat * 8 * 4 * 64) return;
    int lane = idx & 63;
    int ks = (idx >> 6) & 3;
    int nt = (idx >> 8) & 7;
    int m  = idx >> 11;
    int n  = nt * 16 + (lane & 15);
    int k0 = ks * 32 + (lane >> 4) * 8;
    const float* Wp = W + (size_t)m * INF_ * FF;
    unsigned int u0 = bf16pair(Wp[(k0 + 0) * FF + n], Wp[(k0 + 1) * FF + n]);
    unsigned int u1 = bf16pair(Wp[(k0 + 2) * FF + n], Wp[(k0 + 3) * FF + n]);
    unsigned int u2 = bf16pair(Wp[(k0 + 4) * FF + n], Wp[(k0 + 5) * FF + n]);
    unsigned int u3 = bf16pair(Wp[(k0 + 6) * FF + n], Wp[(k0 + 7) * FF + n]);
    *(uint4*)&Wpack[(size_t)idx * 8] = make_uint4(u0, u1, u2, u3);
}

// K1: feat[p] = h @ W[p] via bf16 MFMA. 4 waves/block; wave = 16 rows x 128 cols.
__global__ __launch_bounds__(256) void k1_mfma(const unsigned short* __restrict__ hb16,
                        const unsigned short* __restrict__ Wpack,
                        const float* __restrict__ al, const float* __restrict__ ar,
                        unsigned int* __restrict__ featb, float* __restrict__ el,
                        float* __restrict__ er, int N) {
    int l = threadIdx.x & 63;
    int wu = threadIdx.x >> 6;
    int p = blockIdx.y;
    int rowbase = blockIdx.x * 64 + wu * 16;
    if (rowbase >= N) return;
    int q = l >> 4;
    int t16 = l & 15;
    int arow = rowbase + t16; if (arow > N - 1) arow = N - 1;
    const unsigned short* hrow = hb16 + (size_t)arow * INF_ + q * 8;
    const unsigned short* wp = Wpack + (size_t)p * 8 * 4 * 64 * 8;

    f32x4 acc[8];
#pragma unroll
    for (int i = 0; i < 8; ++i) acc[i] = (f32x4){0.f, 0.f, 0.f, 0.f};

#pragma unroll
    for (int ks = 0; ks < 4; ++ks) {
        bf16x8 av = *(const bf16x8*)&hrow[ks * 32];
#pragma unroll
        for (int nt = 0; nt < 8; ++nt) {
            bf16x8 bv = *(const bf16x8*)&wp[(((size_t)nt * 4 + ks) * 64 + l) * 8];
            acc[nt] = __builtin_amdgcn_mfma_f32_16x16x32_bf16(av, bv, acc[nt], 0, 0, 0);
        }
    }

    float alv[8], arv[8];
#pragma unroll
    for (int nt = 0; nt < 8; ++nt) {
        int cc = (nt & 1) * 16 + t16;
        alv[nt] = al[((size_t)p * HH + (nt >> 1)) * DD + cc];
        arv[nt] = ar[((size_t)p * HH + (nt >> 1)) * DD + cc];
    }
    float elp[4][4], erp[4][4];
#pragma unroll
    for (int r = 0; r < 4; ++r)
#pragma unroll
        for (int hd = 0; hd < 4; ++hd) { elp[r][hd] = 0.f; erp[r][hd] = 0.f; }
#pragma unroll
    for (int nt = 0; nt < 8; ++nt)
#pragma unroll
        for (int r = 0; r < 4; ++r) {
            elp[r][nt >> 1] = fmaf(acc[nt][r], alv[nt], elp[r][nt >> 1]);
            erp[r][nt >> 1] = fmaf(acc[nt][r], arv[nt], erp[r][nt >> 1]);
        }
#pragma unroll
    for (int r = 0; r < 4; ++r)
#pragma unroll
        for (int hd = 0; hd < 4; ++hd) {
#pragma unroll
            for (int off = 8; off >= 1; off >>= 1) {
                elp[r][hd] += __shfl_xor(elp[r][hd], off);
                erp[r][hd] += __shfl_xor(erp[r][hd], off);
            }
        }

#pragma unroll
    for (int r = 0; r < 4; ++r) {
        int row = rowbase + q * 4 + r;
        bool vr = row < N;
        if (t16 == 0 && vr) {
#pragma unroll
            for (int hd = 0; hd < 4; ++hd) {
                el[((size_t)p * N + row) * HH + hd] = elp[r][hd];
                er[((size_t)p * N + row) * HH + hd] = erp[r][hd];
            }
        }
#pragma unroll
        for (int nt = 0; nt < 8; ++nt) {
            float partner = __shfl_xor(acc[nt][r], 1);
            if ((l & 1) == 0 && vr) {
                int j = nt * 8 + (t16 >> 1);
                featb[((size_t)p * N + row) * 64 + j] = bf16pair(acc[nt][r], partner);
            }
        }
    }
}

// KA: bucket-partition edges by dst>>9. Per 2048-edge block: LDS histogram,
// one global atomicAdd per bucket reserves a dense run, edges written packed
// (src<<9 | dst&511) 4B each. All register arrays constant-indexed.
__global__ __launch_bounds__(256) void kA_bucket(const int* __restrict__ src,
        const int* __restrict__ dst, int* __restrict__ gcur,
        unsigned int* __restrict__ barr, int E) {
    __shared__ int cnt[128];
    __shared__ int gbase[128];
    int p = blockIdx.y;
    int t = threadIdx.x;
    int base = blockIdx.x * (ACH * 256);
    const int* sp = src + (size_t)p * E;
    const int* dp = dst + (size_t)p * E;
    if (t < 128) cnt[t] = 0;
    __syncthreads();
    int sv[ACH], dv[ACH], rv[ACH];
    bool val[ACH];
#pragma unroll
    for (int j = 0; j < ACH; ++j) {
        int idx = base + j * 256 + t;
        val[j] = idx < E;
        int ci = val[j] ? idx : (E - 1);
        dv[j] = dp[ci];
        sv[j] = sp[ci];
    }
#pragma unroll
    for (int j = 0; j < ACH; ++j)
        rv[j] = val[j] ? atomicAdd(&cnt[dv[j] >> BSHIFT], 1) : 0;
    __syncthreads();
    if (t < 128) gbase[t] = atomicAdd(&gcur[p * 128 + t], cnt[t]);
    __syncthreads();
#pragma unroll
    for (int j = 0; j < ACH; ++j) {
        if (val[j]) {
            int b = dv[j] >> BSHIFT;
            int posn = gbase[b] + rv[j];
            if (posn >= BCAP) posn = BCAP - 1;   // statistically impossible guard
            barr[(size_t)(p * 128 + b) * BCAP + posn] =
                ((unsigned int)sv[j] << BSHIFT) | (unsigned int)(dv[j] & (BW - 1));
        }
    }
}

// KScan: exclusive scan of per-bucket counts -> bucket bases; offs[N]=E.
__global__ __launch_bounds__(128) void kscan_buckets(const int* __restrict__ gcur,
        int* __restrict__ bukbase, int* __restrict__ offs, int N, int E, int nbuk) {
    __shared__ int sc[128];
    int t = threadIdx.x;
    for (int p = 0; p < PP; ++p) {
        int v = (t < nbuk) ? gcur[p * 128 + t] : 0;
        sc[t] = v;
        __syncthreads();
        for (int off = 1; off < 128; off <<= 1) {
            int u = (t >= off) ? sc[t - off] : 0;
            __syncthreads();
            sc[t] += u;
            __syncthreads();
        }
        if (t < nbuk) bukbase[p * 128 + t] = sc[t] - v;
        if (t == 0) offs[(size_t)p * (N + 1) + N] = E;
        __syncthreads();
    }
}

// KB: per-(bucket,path) CSR build entirely in LDS: histogram -> scan ->
// offs (coalesced) -> LDS scatter -> dense csr writeout (dwordx4).
__global__ __launch_bounds__(512) void kB_build(const unsigned int* __restrict__ barr,
        const int* __restrict__ gcur, const int* __restrict__ bukbase,
        int* __restrict__ offs, int* __restrict__ csr, int N, int E) {
    __shared__ int cnt[BW];
    __shared__ int curs[BW];
    __shared__ int slice[BCAP];   // 40 KB (also scan scratch)
    int p = blockIdx.y, b = blockIdx.x;
    int t = threadIdx.x;
    int n0 = b << BSHIFT;
    int ncnt = N - n0; if (ncnt > BW) ncnt = BW;
    int ecnt = gcur[p * 128 + b]; if (ecnt > BCAP) ecnt = BCAP;
    int gb = bukbase[p * 128 + b];
    const unsigned int* ba = barr + (size_t)(p * 128 + b) * BCAP;
    cnt[t] = 0;
    __syncthreads();
    for (int i = t; i < ecnt; i += BW)
        atomicAdd(&cnt[ba[i] & (BW - 1u)], 1);
    __syncthreads();
    int myc = (t < ncnt) ? cnt[t] : 0;
    slice[t] = myc;
    __syncthreads();
    for (int off = 1; off < BW; off <<= 1) {
        int v = (t >= off) ? slice[t - off] : 0;
        __syncthreads();
        slice[t] += v;
        __syncthreads();
    }
    int excl = slice[t] - myc;
    if (t < ncnt) {
        curs[t] = excl;
        offs[(size_t)p * (N + 1) + n0 + t] = gb + excl;
    }
    __syncthreads();
    for (int i = t; i < ecnt; i += BW) {
        unsigned int v = ba[i];
        int pos = atomicAdd(&curs[v & (BW - 1u)], 1);
        slice[pos] = (int)(v >> BSHIFT);
    }
    __syncthreads();
    for (int i = t; i < ecnt; i += BW)
        csr[(size_t)p * E + gb + i] = slice[i];
}

// K5: per-(node,path) single-pass softmax aggregation. Each lane computes all
// 4 head-exps for ITS one loaded edge, stashes to LDS; inner loop broadcasts
// via ds_read. Emits z fp32 (k8 path) AND packed bf16 (k6 MFMA).
__global__ __launch_bounds__(256) void k5_aggregate(const unsigned int* __restrict__ featb,
                             const float* __restrict__ el, const float* __restrict__ er,
                             const float* __restrict__ bias,
                             const int* __restrict__ offs, const int* __restrict__ csr,
                             float* __restrict__ z, unsigned int* __restrict__ zb16,
                             int N, int E) {
    __shared__ float wbuf[4][64][HH];   // 4 KB
    int w = threadIdx.x >> 6, l = threadIdx.x & 63;
    int n = blockIdx.x * 4 + w;
    int p = blockIdx.y;
    if (n >= N) return;
    int hd = l >> 4;
    int c0 = 2 * l;
    const float* elp = el + (size_t)p * N * HH;
    const float* erp = er + (size_t)p * N * HH;
    float4 rv = *(const float4*)&erp[(size_t)n * HH];
    int j0 = offs[(size_t)p * (N + 1) + n];
    int j1 = offs[(size_t)p * (N + 1) + n + 1];
    const int* cs = csr + (size_t)p * E;
    const unsigned int* fp = featb + (size_t)p * N * 64;
    float acc0 = 0.f, acc1 = 0.f, sumw = 0.f;
    for (int base = j0; base < j1; base += 64) {
        int rem = j1 - base;
        int cnt = rem > 64 ? 64 : rem;
        int mysn = (l < cnt) ? cs[base + l] : 0;
        float4 ev = *(const float4*)&elp[(size_t)mysn * HH];
        float4 wv;
        float e;
        e = ev.x + rv.x; e = fmaxf(e, NEG_SLOPE * e); wv.x = __expf(e);
        e = ev.y + rv.y; e = fmaxf(e, NEG_SLOPE * e); wv.y = __expf(e);
        e = ev.z + rv.z; e = fmaxf(e, NEG_SLOPE * e); wv.z = __expf(e);
        e = ev.w + rv.w; e = fmaxf(e, NEG_SLOPE * e); wv.w = __expf(e);
        *(float4*)&wbuf[w][l][0] = wv;
        int tt = 0;
        for (; tt + 4 <= cnt; tt += 4) {
            int s0 = __shfl(mysn, tt);
            int s1 = __shfl(mysn, tt + 1);
            int s2 = __shfl(mysn, tt + 2);
            int s3 = __shfl(mysn, tt + 3);
            unsigned int v0 = fp[(size_t)s0 * 64 + l];
            unsigned int v1 = fp[(size_t)s1 * 64 + l];
            unsigned int v2 = fp[(size_t)s2 * 64 + l];
            unsigned int v3 = fp[(size_t)s3 * 64 + l];
            float w0 = wbuf[w][tt][hd];
            float w1 = wbuf[w][tt + 1][hd];
            float w2 = wbuf[w][tt + 2][hd];
            float w3 = wbuf[w][tt + 3][hd];
            acc0 = fmaf(w0, __uint_as_float(v0 << 16), acc0);
            acc1 = fmaf(w0, __uint_as_float(v0 & 0xFFFF0000u), acc1);
            acc0 = fmaf(w1, __uint_as_float(v1 << 16), acc0);
            acc1 = fmaf(w1, __uint_as_float(v1 & 0xFFFF0000u), acc1);
            acc0 = fmaf(w2, __uint_as_float(v2 << 16), acc0);
            acc1 = fmaf(w2, __uint_as_float(v2 & 0xFFFF0000u), acc1);
            acc0 = fmaf(w3, __uint_as_float(v3 << 16), acc0);
            acc1 = fmaf(w3, __uint_as_float(v3 & 0xFFFF0000u), acc1);
            sumw += (w0 + w1) + (w2 + w3);
        }
        for (; tt < cnt; ++tt) {
            int s0 = __shfl(mysn, tt);
            unsigned int v0 = fp[(size_t)s0 * 64 + l];
            float w0 = wbuf[w][tt][hd];
            acc0 = fmaf(w0, __uint_as_float(v0 << 16), acc0);
            acc1 = fmaf(w0, __uint_as_float(v0 & 0xFFFF0000u), acc1);
            sumw += w0;
        }
    }
    float inv = 1.f / sumw;
    float2 bv = *(const float2*)&bias[p * FF + c0];
    float z0 = acc0 * inv + bv.x;
    float z1 = acc1 * inv + bv.y;
    z0 = z0 > 0.f ? z0 : __expf(z0) - 1.f;
    z1 = z1 > 0.f ? z1 : __expf(z1) - 1.f;
    size_t zb = ((size_t)p * N + n) * FF;
    *(float2*)&z[zb + c0] = make_float2(z0, z1);
    zb16[((size_t)p * N + n) * 64 + l] = bf16pair(z0, z1);
}

// K6: s[n,p] = tanh(z @ W1 + b1) @ W2 via bf16 MFMA, summed per block.
__global__ __launch_bounds__(256) void k6_mfma(const unsigned int* __restrict__ zb16,
                        const unsigned short* __restrict__ W1pack,
                        const float* __restrict__ b1, const float* __restrict__ W2,
                        float* __restrict__ partials, int N) {
    __shared__ float wsum[4];
    int l = threadIdx.x & 63;
    int wu = threadIdx.x >> 6;
    int p = blockIdx.y;
    int rowbase = blockIdx.x * 64 + wu * 16;
    float ssum = 0.f;
    if (rowbase < N) {
        int q = l >> 4;
        int t16 = l & 15;
        int arow = rowbase + t16; if (arow > N - 1) arow = N - 1;
        const unsigned short* zrow =
            (const unsigned short*)(zb16 + ((size_t)p * N + arow) * 64) + q * 8;

        f32x4 acc[8];
#pragma unroll
        for (int i = 0; i < 8; ++i) acc[i] = (f32x4){0.f, 0.f, 0.f, 0.f};
#pragma unroll
        for (int ks = 0; ks < 4; ++ks) {
            bf16x8 av = *(const bf16x8*)&zrow[ks * 32];
#pragma unroll
            for (int nt = 0; nt < 8; ++nt) {
                bf16x8 bv = *(const bf16x8*)&W1pack[(((size_t)nt * 4 + ks) * 64 + l) * 8];
                acc[nt] = __builtin_amdgcn_mfma_f32_16x16x32_bf16(av, bv, acc[nt], 0, 0, 0);
            }
        }
        float b1v[8], w2v[8];
#pragma unroll
        for (int nt = 0; nt < 8; ++nt) {
            int col = nt * 16 + t16;
            b1v[nt] = b1[col];
            w2v[nt] = W2[col];
        }
        float rowsum[4] = {0.f, 0.f, 0.f, 0.f};
#pragma unroll
        for (int nt = 0; nt < 8; ++nt)
#pragma unroll
            for (int r = 0; r < 4; ++r) {
                float a = acc[nt][r] + b1v[nt];
                float e = __expf(2.f * a);
                float t = 1.f - 2.f * __builtin_amdgcn_rcpf(e + 1.f);
                rowsum[r] = fmaf(t, w2v[nt], rowsum[r]);
            }
#pragma unroll
        for (int r = 0; r < 4; ++r) {
            int row = rowbase + q * 4 + r;
            ssum += (row < N) ? rowsum[r] : 0.f;
        }
#pragma unroll
        for (int off = 32; off >= 1; off >>= 1) ssum += __shfl_xor(ssum, off);
    }
    if (l == 0) wsum[wu] = ssum;
    __syncthreads();
    if (threadIdx.x == 0)
        partials[(size_t)p * gridDim.x + blockIdx.x] = wsum[0] + wsum[1] + wsum[2] + wsum[3];
}

// K7: reduce partials -> w[p] mean -> beta softmax. one block, 3 waves.
__global__ void k7_beta(const float* __restrict__ partials, float* __restrict__ beta,
                        int nblk, int N) {
    __shared__ float wl[3];
    int p = threadIdx.x >> 6, l = threadIdx.x & 63;
    float s = 0.f;
    for (int i = l; i < nblk; i += 64) s += partials[(size_t)p * nblk + i];
    for (int off = 32; off >= 1; off >>= 1) s += __shfl_xor(s, off);
    if (l == 0) wl[p] = s / (float)N;
    __syncthreads();
    if (threadIdx.x == 0) {
        float m = fmaxf(wl[0], fmaxf(wl[1], wl[2]));
        float e0 = __expf(wl[0] - m), e1 = __expf(wl[1] - m), e2 = __expf(wl[2] - m);
        float inv = 1.f / (e0 + e1 + e2);
        beta[0] = e0 * inv; beta[1] = e1 * inv; beta[2] = e2 * inv;
    }
}

// K8: out[n,:] = sum_p beta[p] * z[p][n,:]  (fp32 z path)
__global__ void k8_combine(const float* __restrict__ z, const float* __restrict__ beta,
                           float* __restrict__ out, int N) {
    size_t i = (size_t)blockIdx.x * 256 + threadIdx.x;
    size_t tot = (size_t)N * FF;
    if (i < tot) {
        float b0 = beta[0], b1 = beta[1], b2 = beta[2];
        out[i] = b0 * z[i] + b1 * z[tot + i] + b2 * z[2 * tot + i];
    }
}

extern "C" void kernel_launch(void* const* d_in, const int* in_sizes, int n_in,
                              void* d_out, int out_size, void* d_ws, size_t ws_size,
                              hipStream_t stream) {
    const float* h    = (const float*)d_in[0];
    const float* W    = (const float*)d_in[1];
    const float* al   = (const float*)d_in[2];
    const float* ar   = (const float*)d_in[3];
    const float* bias = (const float*)d_in[4];
    const float* W1   = (const float*)d_in[5];
    const float* b1   = (const float*)d_in[6];
    const float* W2   = (const float*)d_in[7];
    const int*   src  = (const int*)d_in[8];
    const int*   dst  = (const int*)d_in[9];
    float* out = (float*)d_out;

    int N = in_sizes[0] / INF_;
    int E = in_sizes[8] / PP;
    int nbuk = (N + BW - 1) >> BSHIFT;   // 98 for N=50000

    char* ws = (char*)d_ws;
    size_t off = 0;
    auto take = [&](size_t bytes) -> void* {
        off = (off + 255) & ~(size_t)255;
        void* ptr = ws + off;
        off += bytes;
        return ptr;
    };
    unsigned int* featb = (unsigned int*)take((size_t)PP * N * 64 * sizeof(unsigned int));
    float* z        = (float*)take((size_t)PP * N * FF * sizeof(float));
    unsigned int* zb16 = (unsigned int*)take((size_t)PP * N * 64 * sizeof(unsigned int));
    float* el       = (float*)take((size_t)PP * N * HH * sizeof(float));
    float* er       = (float*)take((size_t)PP * N * HH * sizeof(float));
    int*   offs     = (int*)take((size_t)PP * (N + 1) * sizeof(int));
    int*   csr      = (int*)take((size_t)PP * E * sizeof(int));
    unsigned int* barr = (unsigned int*)take((size_t)PP * 128 * BCAP * sizeof(unsigned int));
    int*   gcur     = (int*)take((size_t)PP * 128 * sizeof(int));
    int*   bukbase  = (int*)take((size_t)PP * 128 * sizeof(int));
    unsigned short* hb16   = (unsigned short*)take((size_t)N * INF_ * sizeof(unsigned short));
    unsigned short* Wpack  = (unsigned short*)take((size_t)PP * 8 * 4 * 64 * 8 * sizeof(unsigned short));
    unsigned short* W1pack = (unsigned short*)take((size_t)8 * 4 * 64 * 8 * sizeof(unsigned short));
    int    nblkM    = (N + 63) / 64;
    int    nblk4    = (N + 3) / 4;
    float* partials = (float*)take((size_t)PP * nblkM * sizeof(float));
    float* betap    = (float*)take(16);
    (void)ws_size; (void)n_in; (void)out_size;

    hipMemsetAsync(gcur, 0, (size_t)PP * 128 * sizeof(int), stream);

    int total4 = N * INF_ / 4;
    dim3 gM(nblkM, PP);
    dim3 gNode(nblk4, PP);
    dim3 gA((E + ACH * 256 - 1) / (ACH * 256), PP);
    dim3 gB(nbuk, PP);

    kh_conv<<<(total4 + 255) / 256, 256, 0, stream>>>(h, hb16, total4);
    kw_pack<<<(PP * 2048 + 255) / 256, 256, 0, stream>>>(W, Wpack, PP);
    kw_pack<<<(2048 + 255) / 256, 256, 0, stream>>>(W1, W1pack, 1);
    k1_mfma<<<gM, 256, 0, stream>>>(hb16, Wpack, al, ar, featb, el, er, N);
    kA_bucket<<<gA, 256, 0, stream>>>(src, dst, gcur, barr, E);
    kscan_buckets<<<1, 128, 0, stream>>>(gcur, bukbase, offs, N, E, nbuk);
    kB_build<<<gB, 512, 0, stream>>>(barr, gcur, bukbase, offs, csr, N, E);
    k5_aggregate<<<gNode, 256, 0, stream>>>(featb, el, er, bias, offs, csr, z, zb16, N, E);
    k6_mfma<<<gM, 256, 0, stream>>>(zb16, W1pack, b1, W2, partials, N);
    k7_beta<<<1, 192, 0, stream>>>(partials, betap, nblkM, N);
    k8_combine<<<(int)(((size_t)N * FF + 255) / 256), 256, 0, stream>>>(z, betap, out, N);
}

// Round 10
// 314.632 us; speedup vs baseline: 2.7631x; 1.0138x over previous
//
#include <hip/hip_runtime.h>
#include <math.h>

#define PP 3
#define HH 4
#define DD 32
#define FF 128   // H*D
#define INF_ 128 // input feature dim
#define NEG_SLOPE 0.2f

#define BSHIFT 9          // bucket = dst >> 9  (512 nodes/bucket)
#define BW 512            // nodes per bucket
#define BCAP 10240        // max edges per bucket (mean ~8700 -> 17 sigma headroom)
#define ACH 8             // edge rounds per thread in kA (chunk = 2048 edges)

// Column permutation for featb/zb16 rows: word j holds cols (C(j), C(j)+16),
// C(j) = 32*(j>>4) + (j&15). Both cols of a word share head j>>4.
// k6's W1pack applies the matching k-permutation sigma.

typedef __bf16 bf16x8 __attribute__((ext_vector_type(8)));
typedef float f32x4 __attribute__((ext_vector_type(4)));

__device__ __forceinline__ unsigned int bf16pair(float x, float y) {
    unsigned int a = __float_as_uint(x);
    unsigned int b = __float_as_uint(y);
    a = (a + 0x7FFFu + ((a >> 16) & 1u)) >> 16;   // RNE round to bf16
    b = (b + 0x7FFFu + ((b >> 16) & 1u)) >> 16;
    return a | (b << 16);
}

// KH: h fp32 -> bf16 (once); also zeroes gcur (replaces a memset dispatch)
__global__ __launch_bounds__(256) void kh_conv(const float* __restrict__ h,
                                               unsigned short* __restrict__ hb16,
                                               int* __restrict__ gcur,
                                               int total4) {
    int i = blockIdx.x * 256 + threadIdx.x;
    if (i < PP * 128) gcur[i] = 0;
    if (i < total4) {
        float4 v = *(const float4*)&h[(size_t)i * 4];
        unsigned int lo = bf16pair(v.x, v.y);
        unsigned int hi = bf16pair(v.z, v.w);
        *(uint2*)&hb16[(size_t)i * 4] = make_uint2(lo, hi);
    }
}

// KW: pack nmat 128x128 fp32 matrices into B-fragment order for
// mfma_f32_16x16x32_bf16: B[k][n], n=lane&15, k=quad*8+j.
// perm!=0: apply sigma(k) = 32*((k>>1)>>4) + ((k>>1)&15) + 16*(k&1) to the
// k-row index (matches the permuted zb16 word layout).
__global__ __launch_bounds__(256) void kw_pack(const float* __restrict__ W,
                                               unsigned short* __restrict__ Wpack,
                                               int nmat, int perm) {
    int idx = blockIdx.x * 256 + threadIdx.x;
    if (idx >= nmat * 8 * 4 * 64) return;
    int lane = idx & 63;
    int ks = (idx >> 6) & 3;
    int nt = (idx >> 8) & 7;
    int m  = idx >> 11;
    int n  = nt * 16 + (lane & 15);
    int k0 = ks * 32 + (lane >> 4) * 8;
    const float* Wp = W + (size_t)m * INF_ * FF;
    float rowv[8];
#pragma unroll
    for (int i = 0; i < 8; ++i) {
        int k = k0 + i;
        if (perm) {
            int w = k >> 1;
            k = 32 * (w >> 4) + (w & 15) + 16 * (k & 1);
        }
        rowv[i] = Wp[(size_t)k * FF + n];
    }
    unsigned int u0 = bf16pair(rowv[0], rowv[1]);
    unsigned int u1 = bf16pair(rowv[2], rowv[3]);
    unsigned int u2 = bf16pair(rowv[4], rowv[5]);
    unsigned int u3 = bf16pair(rowv[6], rowv[7]);
    *(uint4*)&Wpack[(size_t)idx * 8] = make_uint4(u0, u1, u2, u3);
}

// K1: feat[p] = h @ W[p] via bf16 MFMA. 4 waves/block; wave = 16 rows x 128 cols.
// featb written in permuted word layout: word t16+16*np = pair(acc[2np], acc[2np+1])
// -> all-lane dense stores, no shuffles in the pack.
__global__ __launch_bounds__(256) void k1_mfma(const unsigned short* __restrict__ hb16,
                        const unsigned short* __restrict__ Wpack,
                        const float* __restrict__ al, const float* __restrict__ ar,
                        unsigned int* __restrict__ featb, float* __restrict__ el,
                        float* __restrict__ er, int N) {
    int l = threadIdx.x & 63;
    int wu = threadIdx.x >> 6;
    int p = blockIdx.y;
    int rowbase = blockIdx.x * 64 + wu * 16;
    if (rowbase >= N) return;
    int q = l >> 4;
    int t16 = l & 15;
    int arow = rowbase + t16; if (arow > N - 1) arow = N - 1;
    const unsigned short* hrow = hb16 + (size_t)arow * INF_ + q * 8;
    const unsigned short* wp = Wpack + (size_t)p * 8 * 4 * 64 * 8;

    f32x4 acc[8];
#pragma unroll
    for (int i = 0; i < 8; ++i) acc[i] = (f32x4){0.f, 0.f, 0.f, 0.f};

#pragma unroll
    for (int ks = 0; ks < 4; ++ks) {
        bf16x8 av = *(const bf16x8*)&hrow[ks * 32];
#pragma unroll
        for (int nt = 0; nt < 8; ++nt) {
            bf16x8 bv = *(const bf16x8*)&wp[(((size_t)nt * 4 + ks) * 64 + l) * 8];
            acc[nt] = __builtin_amdgcn_mfma_f32_16x16x32_bf16(av, bv, acc[nt], 0, 0, 0);
        }
    }

    float alv[8], arv[8];
#pragma unroll
    for (int nt = 0; nt < 8; ++nt) {
        int cc = (nt & 1) * 16 + t16;
        alv[nt] = al[((size_t)p * HH + (nt >> 1)) * DD + cc];
        arv[nt] = ar[((size_t)p * HH + (nt >> 1)) * DD + cc];
    }
    float elp[4][4], erp[4][4];
#pragma unroll
    for (int r = 0; r < 4; ++r)
#pragma unroll
        for (int hd = 0; hd < 4; ++hd) { elp[r][hd] = 0.f; erp[r][hd] = 0.f; }
#pragma unroll
    for (int nt = 0; nt < 8; ++nt)
#pragma unroll
        for (int r = 0; r < 4; ++r) {
            elp[r][nt >> 1] = fmaf(acc[nt][r], alv[nt], elp[r][nt >> 1]);
            erp[r][nt >> 1] = fmaf(acc[nt][r], arv[nt], erp[r][nt >> 1]);
        }
#pragma unroll
    for (int r = 0; r < 4; ++r)
#pragma unroll
        for (int hd = 0; hd < 4; ++hd) {
#pragma unroll
            for (int off = 8; off >= 1; off >>= 1) {
                elp[r][hd] += __shfl_xor(elp[r][hd], off);
                erp[r][hd] += __shfl_xor(erp[r][hd], off);
            }
        }

#pragma unroll
    for (int r = 0; r < 4; ++r) {
        int row = rowbase + q * 4 + r;
        bool vr = row < N;
        if (vr) {
            unsigned int* frow = featb + ((size_t)p * N + row) * 64;
#pragma unroll
            for (int np = 0; np < 4; ++np)
                frow[t16 + 16 * np] = bf16pair(acc[2 * np][r], acc[2 * np + 1][r]);
            if (t16 == 0) {
#pragma unroll
                for (int hd = 0; hd < 4; ++hd) {
                    el[((size_t)p * N + row) * HH + hd] = elp[r][hd];
                    er[((size_t)p * N + row) * HH + hd] = erp[r][hd];
                }
            }
        }
    }
}

// KA: bucket-partition edges by dst>>9. Per 2048-edge block: LDS histogram,
// one global atomicAdd per bucket reserves a dense run, edges written packed
// (src<<9 | dst&511) 4B each.
__global__ __launch_bounds__(256) void kA_bucket(const int* __restrict__ src,
        const int* __restrict__ dst, int* __restrict__ gcur,
        unsigned int* __restrict__ barr, int E) {
    __shared__ int cnt[128];
    __shared__ int gbase[128];
    int p = blockIdx.y;
    int t = threadIdx.x;
    int base = blockIdx.x * (ACH * 256);
    const int* sp = src + (size_t)p * E;
    const int* dp = dst + (size_t)p * E;
    if (t < 128) cnt[t] = 0;
    __syncthreads();
    int sv[ACH], dv[ACH], rv[ACH];
    bool val[ACH];
#pragma unroll
    for (int j = 0; j < ACH; ++j) {
        int idx = base + j * 256 + t;
        val[j] = idx < E;
        int ci = val[j] ? idx : (E - 1);
        dv[j] = dp[ci];
        sv[j] = sp[ci];
    }
#pragma unroll
    for (int j = 0; j < ACH; ++j)
        rv[j] = val[j] ? atomicAdd(&cnt[dv[j] >> BSHIFT], 1) : 0;
    __syncthreads();
    if (t < 128) gbase[t] = atomicAdd(&gcur[p * 128 + t], cnt[t]);
    __syncthreads();
#pragma unroll
    for (int j = 0; j < ACH; ++j) {
        if (val[j]) {
            int b = dv[j] >> BSHIFT;
            int posn = gbase[b] + rv[j];
            if (posn >= BCAP) posn = BCAP - 1;
            barr[(size_t)(p * 128 + b) * BCAP + posn] =
                ((unsigned int)sv[j] << BSHIFT) | (unsigned int)(dv[j] & (BW - 1));
        }
    }
}

// KScan: exclusive scan of per-bucket counts -> bucket bases; offs[N]=E.
__global__ __launch_bounds__(128) void kscan_buckets(const int* __restrict__ gcur,
        int* __restrict__ bukbase, int* __restrict__ offs, int N, int E, int nbuk) {
    __shared__ int sc[128];
    int t = threadIdx.x;
    for (int p = 0; p < PP; ++p) {
        int v = (t < nbuk) ? gcur[p * 128 + t] : 0;
        sc[t] = v;
        __syncthreads();
        for (int off = 1; off < 128; off <<= 1) {
            int u = (t >= off) ? sc[t - off] : 0;
            __syncthreads();
            sc[t] += u;
            __syncthreads();
        }
        if (t < nbuk) bukbase[p * 128 + t] = sc[t] - v;
        if (t == 0) offs[(size_t)p * (N + 1) + N] = E;
        __syncthreads();
    }
}

// KB: per-(bucket,path) CSR build entirely in LDS.
__global__ __launch_bounds__(512) void kB_build(const unsigned int* __restrict__ barr,
        const int* __restrict__ gcur, const int* __restrict__ bukbase,
        int* __restrict__ offs, int* __restrict__ csr, int N, int E) {
    __shared__ int cnt[BW];
    __shared__ int curs[BW];
    __shared__ int slice[BCAP];   // 40 KB
    int p = blockIdx.y, b = blockIdx.x;
    int t = threadIdx.x;
    int n0 = b << BSHIFT;
    int ncnt = N - n0; if (ncnt > BW) ncnt = BW;
    int ecnt = gcur[p * 128 + b]; if (ecnt > BCAP) ecnt = BCAP;
    int gb = bukbase[p * 128 + b];
    const unsigned int* ba = barr + (size_t)(p * 128 + b) * BCAP;
    cnt[t] = 0;
    __syncthreads();
    for (int i = t; i < ecnt; i += BW)
        atomicAdd(&cnt[ba[i] & (BW - 1u)], 1);
    __syncthreads();
    int myc = (t < ncnt) ? cnt[t] : 0;
    slice[t] = myc;
    __syncthreads();
    for (int off = 1; off < BW; off <<= 1) {
        int v = (t >= off) ? slice[t - off] : 0;
        __syncthreads();
        slice[t] += v;
        __syncthreads();
    }
    int excl = slice[t] - myc;
    if (t < ncnt) {
        curs[t] = excl;
        offs[(size_t)p * (N + 1) + n0 + t] = gb + excl;
    }
    __syncthreads();
    for (int i = t; i < ecnt; i += BW) {
        unsigned int v = ba[i];
        int pos = atomicAdd(&curs[v & (BW - 1u)], 1);
        slice[pos] = (int)(v >> BSHIFT);
    }
    __syncthreads();
    for (int i = t; i < ecnt; i += BW)
        csr[(size_t)p * E + gb + i] = slice[i];
}

// K5: per-(node,path) single-pass softmax aggregation. Lane l owns cols
// (C(l), C(l)+16), head l>>4. 8-edge unrolled gather for ILP.
__global__ __launch_bounds__(256) void k5_aggregate(const unsigned int* __restrict__ featb,
                             const float* __restrict__ el, const float* __restrict__ er,
                             const float* __restrict__ bias,
                             const int* __restrict__ offs, const int* __restrict__ csr,
                             float* __restrict__ z, unsigned int* __restrict__ zb16,
                             int N, int E) {
    __shared__ float wbuf[4][64][HH];   // 4 KB
    int w = threadIdx.x >> 6, l = threadIdx.x & 63;
    int n = blockIdx.x * 4 + w;
    int p = blockIdx.y;
    if (n >= N) return;
    int hd = l >> 4;
    int ca = 32 * (l >> 4) + (l & 15);   // first owned col; second = ca+16
    const float* elp = el + (size_t)p * N * HH;
    const float* erp = er + (size_t)p * N * HH;
    float4 rv = *(const float4*)&erp[(size_t)n * HH];
    int j0 = offs[(size_t)p * (N + 1) + n];
    int j1 = offs[(size_t)p * (N + 1) + n + 1];
    const int* cs = csr + (size_t)p * E;
    const unsigned int* fp = featb + (size_t)p * N * 64;
    float acc0 = 0.f, acc1 = 0.f, sumw = 0.f;
    for (int base = j0; base < j1; base += 64) {
        int rem = j1 - base;
        int cnt = rem > 64 ? 64 : rem;
        int mysn = (l < cnt) ? cs[base + l] : 0;
        float4 ev = *(const float4*)&elp[(size_t)mysn * HH];
        float4 wv;
        float e;
        e = ev.x + rv.x; e = fmaxf(e, NEG_SLOPE * e); wv.x = __expf(e);
        e = ev.y + rv.y; e = fmaxf(e, NEG_SLOPE * e); wv.y = __expf(e);
        e = ev.z + rv.z; e = fmaxf(e, NEG_SLOPE * e); wv.z = __expf(e);
        e = ev.w + rv.w; e = fmaxf(e, NEG_SLOPE * e); wv.w = __expf(e);
        *(float4*)&wbuf[w][l][0] = wv;
        int tt = 0;
        for (; tt + 8 <= cnt; tt += 8) {
            int s0 = __shfl(mysn, tt);
            int s1 = __shfl(mysn, tt + 1);
            int s2 = __shfl(mysn, tt + 2);
            int s3 = __shfl(mysn, tt + 3);
            int s4 = __shfl(mysn, tt + 4);
            int s5 = __shfl(mysn, tt + 5);
            int s6 = __shfl(mysn, tt + 6);
            int s7 = __shfl(mysn, tt + 7);
            unsigned int v0 = fp[(size_t)s0 * 64 + l];
            unsigned int v1 = fp[(size_t)s1 * 64 + l];
            unsigned int v2 = fp[(size_t)s2 * 64 + l];
            unsigned int v3 = fp[(size_t)s3 * 64 + l];
            unsigned int v4 = fp[(size_t)s4 * 64 + l];
            unsigned int v5 = fp[(size_t)s5 * 64 + l];
            unsigned int v6 = fp[(size_t)s6 * 64 + l];
            unsigned int v7 = fp[(size_t)s7 * 64 + l];
            float w0 = wbuf[w][tt][hd];
            float w1 = wbuf[w][tt + 1][hd];
            float w2 = wbuf[w][tt + 2][hd];
            float w3 = wbuf[w][tt + 3][hd];
            float w4 = wbuf[w][tt + 4][hd];
            float w5 = wbuf[w][tt + 5][hd];
            float w6 = wbuf[w][tt + 6][hd];
            float w7 = wbuf[w][tt + 7][hd];
            acc0 = fmaf(w0, __uint_as_float(v0 << 16), acc0);
            acc1 = fmaf(w0, __uint_as_float(v0 & 0xFFFF0000u), acc1);
            acc0 = fmaf(w1, __uint_as_float(v1 << 16), acc0);
            acc1 = fmaf(w1, __uint_as_float(v1 & 0xFFFF0000u), acc1);
            acc0 = fmaf(w2, __uint_as_float(v2 << 16), acc0);
            acc1 = fmaf(w2, __uint_as_float(v2 & 0xFFFF0000u), acc1);
            acc0 = fmaf(w3, __uint_as_float(v3 << 16), acc0);
            acc1 = fmaf(w3, __uint_as_float(v3 & 0xFFFF0000u), acc1);
            acc0 = fmaf(w4, __uint_as_float(v4 << 16), acc0);
            acc1 = fmaf(w4, __uint_as_float(v4 & 0xFFFF0000u), acc1);
            acc0 = fmaf(w5, __uint_as_float(v5 << 16), acc0);
            acc1 = fmaf(w5, __uint_as_float(v5 & 0xFFFF0000u), acc1);
            acc0 = fmaf(w6, __uint_as_float(v6 << 16), acc0);
            acc1 = fmaf(w6, __uint_as_float(v6 & 0xFFFF0000u), acc1);
            acc0 = fmaf(w7, __uint_as_float(v7 << 16), acc0);
            acc1 = fmaf(w7, __uint_as_float(v7 & 0xFFFF0000u), acc1);
            sumw += ((w0 + w1) + (w2 + w3)) + ((w4 + w5) + (w6 + w7));
        }
        for (; tt < cnt; ++tt) {
            int s0 = __shfl(mysn, tt);
            unsigned int v0 = fp[(size_t)s0 * 64 + l];
            float w0 = wbuf[w][tt][hd];
            acc0 = fmaf(w0, __uint_as_float(v0 << 16), acc0);
            acc1 = fmaf(w0, __uint_as_float(v0 & 0xFFFF0000u), acc1);
            sumw += w0;
        }
    }
    float inv = 1.f / sumw;
    float bv0 = bias[p * FF + ca];
    float bv1 = bias[p * FF + ca + 16];
    float z0 = acc0 * inv + bv0;
    float z1 = acc1 * inv + bv1;
    z0 = z0 > 0.f ? z0 : __expf(z0) - 1.f;
    z1 = z1 > 0.f ? z1 : __expf(z1) - 1.f;
    size_t zb = ((size_t)p * N + n) * FF;
    z[zb + ca] = z0;
    z[zb + ca + 16] = z1;
    zb16[((size_t)p * N + n) * 64 + l] = bf16pair(z0, z1);
}

// K6: s[n,p] = tanh(z @ W1 + b1) @ W2 via bf16 MFMA (W1pack k-permuted to
// match zb16 word layout), summed per block.
__global__ __launch_bounds__(256) void k6_mfma(const unsigned int* __restrict__ zb16,
                        const unsigned short* __restrict__ W1pack,
                        const float* __restrict__ b1, const float* __restrict__ W2,
                        float* __restrict__ partials, int N) {
    __shared__ float wsum[4];
    int l = threadIdx.x & 63;
    int wu = threadIdx.x >> 6;
    int p = blockIdx.y;
    int rowbase = blockIdx.x * 64 + wu * 16;
    float ssum = 0.f;
    if (rowbase < N) {
        int q = l >> 4;
        int t16 = l & 15;
        int arow = rowbase + t16; if (arow > N - 1) arow = N - 1;
        const unsigned short* zrow =
            (const unsigned short*)(zb16 + ((size_t)p * N + arow) * 64) + q * 8;

        f32x4 acc[8];
#pragma unroll
        for (int i = 0; i < 8; ++i) acc[i] = (f32x4){0.f, 0.f, 0.f, 0.f};
#pragma unroll
        for (int ks = 0; ks < 4; ++ks) {
            bf16x8 av = *(const bf16x8*)&zrow[ks * 32];
#pragma unroll
            for (int nt = 0; nt < 8; ++nt) {
                bf16x8 bv = *(const bf16x8*)&W1pack[(((size_t)nt * 4 + ks) * 64 + l) * 8];
                acc[nt] = __builtin_amdgcn_mfma_f32_16x16x32_bf16(av, bv, acc[nt], 0, 0, 0);
            }
        }
        float b1v[8], w2v[8];
#pragma unroll
        for (int nt = 0; nt < 8; ++nt) {
            int col = nt * 16 + t16;
            b1v[nt] = b1[col];
            w2v[nt] = W2[col];
        }
        float rowsum[4] = {0.f, 0.f, 0.f, 0.f};
#pragma unroll
        for (int nt = 0; nt < 8; ++nt)
#pragma unroll
            for (int r = 0; r < 4; ++r) {
                float a = acc[nt][r] + b1v[nt];
                float e = __expf(2.f * a);
                float t = 1.f - 2.f * __builtin_amdgcn_rcpf(e + 1.f);
                rowsum[r] = fmaf(t, w2v[nt], rowsum[r]);
            }
#pragma unroll
        for (int r = 0; r < 4; ++r) {
            int row = rowbase + q * 4 + r;
            ssum += (row < N) ? rowsum[r] : 0.f;
        }
#pragma unroll
        for (int off = 32; off >= 1; off >>= 1) ssum += __shfl_xor(ssum, off);
    }
    if (l == 0) wsum[wu] = ssum;
    __syncthreads();
    if (threadIdx.x == 0)
        partials[(size_t)p * gridDim.x + blockIdx.x] = wsum[0] + wsum[1] + wsum[2] + wsum[3];
}

// K7: reduce partials -> w[p] mean -> beta softmax. one block, 3 waves.
__global__ void k7_beta(const float* __restrict__ partials, float* __restrict__ beta,
                        int nblk, int N) {
    __shared__ float wl[3];
    int p = threadIdx.x >> 6, l = threadIdx.x & 63;
    float s = 0.f;
    for (int i = l; i < nblk; i += 64) s += partials[(size_t)p * nblk + i];
    for (int off = 32; off >= 1; off >>= 1) s += __shfl_xor(s, off);
    if (l == 0) wl[p] = s / (float)N;
    __syncthreads();
    if (threadIdx.x == 0) {
        float m = fmaxf(wl[0], fmaxf(wl[1], wl[2]));
        float e0 = __expf(wl[0] - m), e1 = __expf(wl[1] - m), e2 = __expf(wl[2] - m);
        float inv = 1.f / (e0 + e1 + e2);
        beta[0] = e0 * inv; beta[1] = e1 * inv; beta[2] = e2 * inv;
    }
}

// K8: out[n,:] = sum_p beta[p] * z[p][n,:]  (fp32, float4 vectorized)
__global__ void k8_combine(const float* __restrict__ z, const float* __restrict__ beta,
                           float* __restrict__ out, int N) {
    size_t i = (size_t)blockIdx.x * 256 + threadIdx.x;
    size_t tot4 = (size_t)N * FF / 4;
    if (i < tot4) {
        float b0 = beta[0], b1 = beta[1], b2 = beta[2];
        const float4* z4 = (const float4*)z;
        float4 a = z4[i], b = z4[tot4 + i], c = z4[2 * tot4 + i];
        float4 o;
        o.x = b0 * a.x + b1 * b.x + b2 * c.x;
        o.y = b0 * a.y + b1 * b.y + b2 * c.y;
        o.z = b0 * a.z + b1 * b.z + b2 * c.z;
        o.w = b0 * a.w + b1 * b.w + b2 * c.w;
        ((float4*)out)[i] = o;
    }
}

extern "C" void kernel_launch(void* const* d_in, const int* in_sizes, int n_in,
                              void* d_out, int out_size, void* d_ws, size_t ws_size,
                              hipStream_t stream) {
    const float* h    = (const float*)d_in[0];
    const float* W    = (const float*)d_in[1];
    const float* al   = (const float*)d_in[2];
    const float* ar   = (const float*)d_in[3];
    const float* bias = (const float*)d_in[4];
    const float* W1   = (const float*)d_in[5];
    const float* b1   = (const float*)d_in[6];
    const float* W2   = (const float*)d_in[7];
    const int*   src  = (const int*)d_in[8];
    const int*   dst  = (const int*)d_in[9];
    float* out = (float*)d_out;

    int N = in_sizes[0] / INF_;
    int E = in_sizes[8] / PP;
    int nbuk = (N + BW - 1) >> BSHIFT;

    char* ws = (char*)d_ws;
    size_t off = 0;
    auto take = [&](size_t bytes) -> void* {
        off = (off + 255) & ~(size_t)255;
        void* ptr = ws + off;
        off += bytes;
        return ptr;
    };
    unsigned int* featb = (unsigned int*)take((size_t)PP * N * 64 * sizeof(unsigned int));
    float* z        = (float*)take((size_t)PP * N * FF * sizeof(float));
    unsigned int* zb16 = (unsigned int*)take((size_t)PP * N * 64 * sizeof(unsigned int));
    float* el       = (float*)take((size_t)PP * N * HH * sizeof(float));
    float* er       = (float*)take((size_t)PP * N * HH * sizeof(float));
    int*   offs     = (int*)take((size_t)PP * (N + 1) * sizeof(int));
    int*   csr      = (int*)take((size_t)PP * E * sizeof(int));
    unsigned int* barr = (unsigned int*)take((size_t)PP * 128 * BCAP * sizeof(unsigned int));
    int*   gcur     = (int*)take((size_t)PP * 128 * sizeof(int));
    int*   bukbase  = (int*)take((size_t)PP * 128 * sizeof(int));
    unsigned short* hb16   = (unsigned short*)take((size_t)N * INF_ * sizeof(unsigned short));
    unsigned short* Wpack  = (unsigned short*)take((size_t)PP * 8 * 4 * 64 * 8 * sizeof(unsigned short));
    unsigned short* W1pack = (unsigned short*)take((size_t)8 * 4 * 64 * 8 * sizeof(unsigned short));
    int    nblkM    = (N + 63) / 64;
    int    nblk4    = (N + 3) / 4;
    float* partials = (float*)take((size_t)PP * nblkM * sizeof(float));
    float* betap    = (float*)take(16);
    (void)ws_size; (void)n_in; (void)out_size;

    int total4 = N * INF_ / 4;
    dim3 gM(nblkM, PP);
    dim3 gNode(nblk4, PP);
    dim3 gA((E + ACH * 256 - 1) / (ACH * 256), PP);
    dim3 gB(nbuk, PP);

    kh_conv<<<(total4 + 255) / 256, 256, 0, stream>>>(h, hb16, gcur, total4);
    kw_pack<<<(PP * 2048 + 255) / 256, 256, 0, stream>>>(W, Wpack, PP, 0);
    kw_pack<<<(2048 + 255) / 256, 256, 0, stream>>>(W1, W1pack, 1, 1);
    k1_mfma<<<gM, 256, 0, stream>>>(hb16, Wpack, al, ar, featb, el, er, N);
    kA_bucket<<<gA, 256, 0, stream>>>(src, dst, gcur, barr, E);
    kscan_buckets<<<1, 128, 0, stream>>>(gcur, bukbase, offs, N, E, nbuk);
    kB_build<<<gB, 512, 0, stream>>>(barr, gcur, bukbase, offs, csr, N, E);
    k5_aggregate<<<gNode, 256, 0, stream>>>(featb, el, er, bias, offs, csr, z, zb16, N, E);
    k6_mfma<<<gM, 256, 0, stream>>>(zb16, W1pack, b1, W2, partials, N);
    k7_beta<<<1, 192, 0, stream>>>(partials, betap, nblkM, N);
    k8_combine<<<(int)(((size_t)N * FF / 4 + 255) / 256), 256, 0, stream>>>(z, betap, out, N);
}